// Round 3
// baseline (6113.481 us; speedup 1.0000x reference)
//
#include <hip/hip_runtime.h>
#include <math.h>

// DGCNN_Reg: B=8, N=4096, k=20.
// Point-major layouts: X[p][c], U[p][o], T[p][o] with p = b*4096 + n.
// Edge conv factorized: y[o,n,k] = U[idx[n,k]][o] + T[n][o];
// BN+LeakyReLU (scale>0) commutes with max over k.

constexpr int NPT = 4096;
constexpr int BATCH = 8;
constexpr int PTS = BATCH * NPT;   // 32768
constexpr int ROWT = 2048;         // PD row-panel size
constexpr float EPS = 1e-5f;
#define KC 16

// ---------------- sum of squares per point ----------------
__global__ __launch_bounds__(256) void sqnorm(const float* __restrict__ X,
                                              float* __restrict__ xx, int C) {
    int p = blockIdx.x * 256 + threadIdx.x;
    if (p >= PTS) return;
    float s = 0.f;
    const float* row = X + (size_t)p * C;
    for (int c = 0; c < C; ++c) s = fmaf(row[c], row[c], s);
    xx[p] = s;
}

// ---------------- pairwise "negative sq dist" panel (one batch, rows [row0,row0+ROWT)) ----
// pd[n-row0][m] = 2*dot(x_n,x_m) - xx[n] - xx[m]
__global__ __launch_bounds__(256) void pd_gemm(const float* __restrict__ X,
                                               const float* __restrict__ xx,
                                               float* __restrict__ pd,
                                               int C, int b, int row0) {
    __shared__ float As[KC][64];
    __shared__ float Bs[KC][64];
    int tid = threadIdx.x;
    int tx = tid & 15;          // col group (4 cols)
    int ty = tid >> 4;          // row group (4 rows)
    int colbase = blockIdx.x * 64;
    int rowbase = row0 + blockIdx.y * 64;
    int p0 = b * NPT;
    int lc = tid & 15;          // staging: channel
    int li = tid >> 4;          // staging: point (strided by 16)
    float acc[4][4] = {};
    for (int c0 = 0; c0 < C; c0 += KC) {
        int c = c0 + lc;
        bool inC = (c < C);
#pragma unroll
        for (int r = 0; r < 4; ++r) {
            int pt = li + r * 16;
            As[lc][pt] = inC ? X[(size_t)(p0 + rowbase + pt) * C + c] : 0.f;
            Bs[lc][pt] = inC ? X[(size_t)(p0 + colbase + pt) * C + c] : 0.f;
        }
        __syncthreads();
#pragma unroll
        for (int cc = 0; cc < KC; ++cc) {
            float a[4], bv[4];
#pragma unroll
            for (int i = 0; i < 4; ++i) a[i] = As[cc][ty * 4 + i];
#pragma unroll
            for (int j = 0; j < 4; ++j) bv[j] = Bs[cc][tx * 4 + j];
#pragma unroll
            for (int i = 0; i < 4; ++i)
#pragma unroll
                for (int j = 0; j < 4; ++j)
                    acc[i][j] = fmaf(a[i], bv[j], acc[i][j]);
        }
        __syncthreads();
    }
#pragma unroll
    for (int i = 0; i < 4; ++i) {
        int r = rowbase + ty * 4 + i;
        float xr = xx[p0 + r];
#pragma unroll
        for (int j = 0; j < 4; ++j) {
            int m = colbase + tx * 4 + j;
            pd[(size_t)(r - row0) * NPT + m] = 2.f * acc[i][j] - xr - xx[p0 + m];
        }
    }
}

// ---------------- top-20 per row (stable, lower index wins ties) ----------------
__global__ __launch_bounds__(256) void topk20(const float* __restrict__ pd,
                                              int* __restrict__ idxout, int b, int row0) {
    int rloc = blockIdx.x * 4 + (threadIdx.x >> 6);
    int lane = threadIdx.x & 63;
    const float* prow = pd + (size_t)rloc * NPT;
    float v[64];
#pragma unroll
    for (int j = 0; j < 64; ++j) v[j] = prow[j * 64 + lane];
    unsigned long long rem = 0ull;      // removed mask (keeps v[] in registers)
    int* op = idxout + (size_t)(b * NPT + row0 + rloc) * 20;
    for (int t = 0; t < 20; ++t) {
        float bv = -3.4e38f;
        int bj = 0;
#pragma unroll
        for (int j = 0; j < 64; ++j) {
            bool ok = !((rem >> j) & 1ull);
            if (ok && v[j] > bv) { bv = v[j]; bj = j; }   // strict > keeps lowest j on tie
        }
        int gi = bj * 64 + lane;
#pragma unroll
        for (int s = 1; s < 64; s <<= 1) {
            float ov = __shfl_xor(bv, s);
            int og = __shfl_xor(gi, s);
            if (ov > bv || (ov == bv && og < gi)) { bv = ov; gi = og; }
        }
        if ((gi & 63) == lane) rem |= 1ull << (gi >> 6);
        if (lane == 0) op[t] = b * NPT + gi;    // global point id
    }
}

// ---------------- U = wA * X, T = (wB - wA) * X  (point-major out) ----------------
__global__ __launch_bounds__(256) void ut_gemm(const float* __restrict__ X,
                                               const float* __restrict__ w,
                                               float* __restrict__ U,
                                               float* __restrict__ T,
                                               int C, int O) {
    __shared__ float Xs[KC][64];
    __shared__ float Wa[KC][64];
    __shared__ float Wt[KC][64];
    int tid = threadIdx.x;
    int tx = tid & 15;          // point group
    int ty = tid >> 4;          // o group
    int pbase = blockIdx.x * 64;
    int obase = blockIdx.y * 64;
    int lc = tid & 15;
    int li = tid >> 4;
    float aU[4][4] = {}, aT[4][4] = {};
    for (int c0 = 0; c0 < C; c0 += KC) {
        int c = c0 + lc;
        bool inC = (c < C);
#pragma unroll
        for (int r = 0; r < 4; ++r) {
            int i = li + r * 16;
            Xs[lc][i] = inC ? X[(size_t)(pbase + i) * C + c] : 0.f;
            float wa = 0.f, wb = 0.f;
            if (inC) {
                const float* wrow = w + (size_t)(obase + i) * (2 * C);
                wa = wrow[c];
                wb = wrow[C + c];
            }
            Wa[lc][i] = wa;
            Wt[lc][i] = wb - wa;
        }
        __syncthreads();
#pragma unroll
        for (int cc = 0; cc < KC; ++cc) {
            float xv[4], wav[4], wtv[4];
#pragma unroll
            for (int i = 0; i < 4; ++i) xv[i] = Xs[cc][tx * 4 + i];
#pragma unroll
            for (int j = 0; j < 4; ++j) { wav[j] = Wa[cc][ty * 4 + j]; wtv[j] = Wt[cc][ty * 4 + j]; }
#pragma unroll
            for (int j = 0; j < 4; ++j)
#pragma unroll
                for (int i = 0; i < 4; ++i) {
                    aU[j][i] = fmaf(wav[j], xv[i], aU[j][i]);
                    aT[j][i] = fmaf(wtv[j], xv[i], aT[j][i]);
                }
        }
        __syncthreads();
    }
#pragma unroll
    for (int j = 0; j < 4; ++j)
#pragma unroll
        for (int i = 0; i < 4; ++i) {
            size_t p = pbase + tx * 4 + i;
            int o = obase + ty * 4 + j;
            U[p * O + o] = aU[j][i];
            T[p * O + o] = aT[j][i];
        }
}

// ---------------- gather neighbors, max over k, BN + LeakyReLU ----------------
__global__ __launch_bounds__(256) void gather_max(const float* __restrict__ U,
                                                  const float* __restrict__ T,
                                                  const int* __restrict__ idx,
                                                  const float* __restrict__ g,
                                                  const float* __restrict__ bb,
                                                  const float* __restrict__ rm,
                                                  const float* __restrict__ rv,
                                                  float* __restrict__ Xout, int O) {
    int ppb = 256 / O;
    int o = threadIdx.x % O;
    int lp = threadIdx.x / O;
    int p = blockIdx.x * ppb + lp;
    const int* ip = idx + (size_t)p * 20;
    float m = -3.4e38f;
#pragma unroll
    for (int k = 0; k < 20; ++k) {
        int j = ip[k];
        m = fmaxf(m, U[(size_t)j * O + o]);
    }
    float pre = m + T[(size_t)p * O + o];
    float scale = g[o] / sqrtf(rv[o] + EPS);
    float y = (pre - rm[o]) * scale + bb[o];
    y = y > 0.f ? y : 0.2f * y;
    Xout[(size_t)p * O + o] = y;
}

// ---------------- fused head: out = wreg . lrelu(bn(w5 . concat(x1..x4))) ----------------
__global__ __launch_bounds__(256) void final_fused(const float* __restrict__ X1,
                                                   const float* __restrict__ X2,
                                                   const float* __restrict__ X3,
                                                   const float* __restrict__ X4,
                                                   const float* __restrict__ w5,
                                                   const float* __restrict__ wreg,
                                                   const float* __restrict__ g,
                                                   const float* __restrict__ bb,
                                                   const float* __restrict__ rm,
                                                   const float* __restrict__ rv,
                                                   float* __restrict__ out) {
    __shared__ float Hs[KC][64];
    __shared__ float Ws[KC][64];
    __shared__ float red[16][64];
    int tid = threadIdx.x;
    int tx = tid & 15;          // point group
    int ty = tid >> 4;          // o group
    int p0 = blockIdx.x * 64;
    int lc = tid & 15;
    int li = tid >> 4;
    float pacc[4] = {0.f, 0.f, 0.f, 0.f};
    for (int ot = 0; ot < 16; ++ot) {
        int o0 = ot * 64;
        float acc[4][4] = {};
        for (int c0 = 0; c0 < 512; c0 += KC) {
            const float* src;
            int coff, Cs;
            if (c0 < 64)       { src = X1; coff = c0;       Cs = 64; }
            else if (c0 < 128) { src = X2; coff = c0 - 64;  Cs = 64; }
            else if (c0 < 256) { src = X3; coff = c0 - 128; Cs = 128; }
            else               { src = X4; coff = c0 - 256; Cs = 256; }
#pragma unroll
            for (int r = 0; r < 4; ++r) {
                int i = li + r * 16;
                Hs[lc][i] = src[(size_t)(p0 + i) * Cs + coff + lc];
                Ws[lc][i] = w5[(size_t)(o0 + i) * 512 + c0 + lc];
            }
            __syncthreads();
#pragma unroll
            for (int cc = 0; cc < KC; ++cc) {
                float h[4], wv[4];
#pragma unroll
                for (int i = 0; i < 4; ++i) h[i] = Hs[cc][tx * 4 + i];
#pragma unroll
                for (int j = 0; j < 4; ++j) wv[j] = Ws[cc][ty * 4 + j];
#pragma unroll
                for (int j = 0; j < 4; ++j)
#pragma unroll
                    for (int i = 0; i < 4; ++i)
                        acc[j][i] = fmaf(wv[j], h[i], acc[j][i]);
            }
            __syncthreads();
        }
#pragma unroll
        for (int j = 0; j < 4; ++j) {
            int o = o0 + ty * 4 + j;
            float scale = g[o] / sqrtf(rv[o] + EPS);
            float sh_rm = rm[o], sh_b = bb[o];
            float wr = wreg[o];
#pragma unroll
            for (int i = 0; i < 4; ++i) {
                float y = (acc[j][i] - sh_rm) * scale + sh_b;
                y = y > 0.f ? y : 0.2f * y;
                pacc[i] = fmaf(wr, y, pacc[i]);
            }
        }
    }
#pragma unroll
    for (int i = 0; i < 4; ++i) red[ty][tx * 4 + i] = pacc[i];
    __syncthreads();
    if (tid < 64) {
        float s = 0.f;
#pragma unroll
        for (int q = 0; q < 16; ++q) s += red[q][tid];
        out[p0 + tid] = s;
    }
}

extern "C" void kernel_launch(void* const* d_in, const int* in_sizes, int n_in,
                              void* d_out, int out_size, void* d_ws, size_t ws_size,
                              hipStream_t stream) {
    const float* x    = (const float*)d_in[0];
    const float* w1   = (const float*)d_in[1];
    const float* w2   = (const float*)d_in[2];
    const float* w3   = (const float*)d_in[3];
    const float* w4   = (const float*)d_in[4];
    const float* w5   = (const float*)d_in[5];
    const float* wreg = (const float*)d_in[6];
    const float* bn[5][4];   // g, b, rm, rv per block
    for (int t = 0; t < 5; ++t)
        for (int q = 0; q < 4; ++q)
            bn[t][q] = (const float*)d_in[7 + t * 4 + q];
    float* out = (float*)d_out;

    // workspace layout (bytes), peak ~131 MB.
    // U/T alias the PD slab: PD is dead after topk20, before ut_gemm writes U/T
    // (all kernels are on the same stream, so ordering is strict).
    char* ws = (char*)d_ws;
    size_t o_x1  = 0;
    size_t o_x2  = o_x1  + (size_t)PTS * 64 * 4;    //  8 MB
    size_t o_x3  = o_x2  + (size_t)PTS * 64 * 4;    //  8 MB
    size_t o_x4  = o_x3  + (size_t)PTS * 128 * 4;   // 16 MB
    size_t o_idx = o_x4  + (size_t)PTS * 256 * 4;   // 32 MB
    size_t o_xx  = o_idx + (size_t)PTS * 20 * 4;    // 2.6 MB
    size_t o_pd  = o_xx  + (size_t)PTS * 4;         // 0.13 MB
    size_t o_u   = o_pd;                            // alias: U over PD slab
    size_t o_t   = o_u   + (size_t)PTS * 256 * 4;   // 32 MB after U
    // region size = max(PD = ROWT*NPT*4 = 32 MB, U+T = 64 MB) -> total ~131 MB

    float* X1 = (float*)(ws + o_x1);
    float* X2 = (float*)(ws + o_x2);
    float* X3 = (float*)(ws + o_x3);
    float* X4 = (float*)(ws + o_x4);
    int*   IDX = (int*)(ws + o_idx);
    float* XX = (float*)(ws + o_xx);
    float* PD = (float*)(ws + o_pd);
    float* U  = (float*)(ws + o_u);
    float* T  = (float*)(ws + o_t);

    auto edge_block = [&](const float* Xin, int C, const float* w,
                          const float* const* bnp, float* Xout, int O) {
        sqnorm<<<PTS / 256, 256, 0, stream>>>(Xin, XX, C);
        for (int b = 0; b < BATCH; ++b) {
            for (int row0 = 0; row0 < NPT; row0 += ROWT) {
                pd_gemm<<<dim3(NPT / 64, ROWT / 64), 256, 0, stream>>>(Xin, XX, PD, C, b, row0);
                topk20<<<ROWT / 4, 256, 0, stream>>>(PD, IDX, b, row0);
            }
        }
        ut_gemm<<<dim3(PTS / 64, O / 64), 256, 0, stream>>>(Xin, w, U, T, C, O);
        gather_max<<<PTS * O / 256, 256, 0, stream>>>(U, T, IDX,
                bnp[0], bnp[1], bnp[2], bnp[3], Xout, O);
    };

    edge_block(x,  1,   w1, bn[0], X1, 64);
    edge_block(X1, 64,  w2, bn[1], X2, 64);
    edge_block(X2, 64,  w3, bn[2], X3, 128);
    edge_block(X3, 128, w4, bn[3], X4, 256);

    final_fused<<<PTS / 64, 256, 0, stream>>>(X1, X2, X3, X4, w5, wreg,
            bn[4][0], bn[4][1], bn[4][2], bn[4][3], out);
}

// Round 4
// 4057.138 us; speedup vs baseline: 1.5068x; 1.5068x over previous
//
#include <hip/hip_runtime.h>
#include <math.h>

// DGCNN_Reg: B=8, N=4096, k=20.
// Point-major layouts: X[p][c], U[p][o], T[p][o] with p = b*4096 + n.
// Edge conv factorized: y[o,n,k] = U[idx[n,k]][o] + T[n][o];
// BN+LeakyReLU (scale>0) commutes with max over k.
// R3 fixes: LDS pad 64->68 (kills 16-way staging bank conflicts, was 2.5e8
// conflict cycles in final_fused); head split into partial(16x512 blocks)+reduce
// (occupancy 21%->~100%); full-batch PD panel (topk grid 2x).

constexpr int NPT = 4096;
constexpr int BATCH = 8;
constexpr int PTS = BATCH * NPT;   // 32768
constexpr float EPS = 1e-5f;
#define KC 16
#define PAD 68   // 68 mod 32 = 4 -> staging writes hit 32 distinct banks (2-way max)

// ---------------- sum of squares per point ----------------
__global__ __launch_bounds__(256) void sqnorm(const float* __restrict__ X,
                                              float* __restrict__ xx, int C) {
    int p = blockIdx.x * 256 + threadIdx.x;
    if (p >= PTS) return;
    float s = 0.f;
    const float* row = X + (size_t)p * C;
    for (int c = 0; c < C; ++c) s = fmaf(row[c], row[c], s);
    xx[p] = s;
}

// ---------------- pairwise "negative sq dist" (one batch) ----------------
// pd[n][m] = 2*dot(x_n,x_m) - xx[n] - xx[m]
__global__ __launch_bounds__(256) void pd_gemm(const float* __restrict__ X,
                                               const float* __restrict__ xx,
                                               float* __restrict__ pd,
                                               int C, int b) {
    __shared__ float As[KC][PAD];
    __shared__ float Bs[KC][PAD];
    int tid = threadIdx.x;
    int tx = tid & 15;          // col group (4 cols)
    int ty = tid >> 4;          // row group (4 rows)
    int colbase = blockIdx.x * 64;
    int rowbase = blockIdx.y * 64;
    int p0 = b * NPT;
    int lc = tid & 15;          // staging: channel
    int li = tid >> 4;          // staging: point (strided by 16)
    float acc[4][4] = {};
    for (int c0 = 0; c0 < C; c0 += KC) {
        int c = c0 + lc;
        bool inC = (c < C);
#pragma unroll
        for (int r = 0; r < 4; ++r) {
            int pt = li + r * 16;
            As[lc][pt] = inC ? X[(size_t)(p0 + rowbase + pt) * C + c] : 0.f;
            Bs[lc][pt] = inC ? X[(size_t)(p0 + colbase + pt) * C + c] : 0.f;
        }
        __syncthreads();
#pragma unroll
        for (int cc = 0; cc < KC; ++cc) {
            float a[4], bv[4];
#pragma unroll
            for (int i = 0; i < 4; ++i) a[i] = As[cc][ty * 4 + i];
#pragma unroll
            for (int j = 0; j < 4; ++j) bv[j] = Bs[cc][tx * 4 + j];
#pragma unroll
            for (int i = 0; i < 4; ++i)
#pragma unroll
                for (int j = 0; j < 4; ++j)
                    acc[i][j] = fmaf(a[i], bv[j], acc[i][j]);
        }
        __syncthreads();
    }
#pragma unroll
    for (int i = 0; i < 4; ++i) {
        int r = rowbase + ty * 4 + i;
        float xr = xx[p0 + r];
#pragma unroll
        for (int j = 0; j < 4; ++j) {
            int m = colbase + tx * 4 + j;
            pd[(size_t)r * NPT + m] = 2.f * acc[i][j] - xr - xx[p0 + m];
        }
    }
}

// ---------------- top-20 per row (stable, lower index wins ties) ----------------
__global__ __launch_bounds__(256) void topk20(const float* __restrict__ pd,
                                              int* __restrict__ idxout, int b) {
    int row = blockIdx.x * 4 + (threadIdx.x >> 6);
    int lane = threadIdx.x & 63;
    const float* prow = pd + (size_t)row * NPT;
    float v[64];
#pragma unroll
    for (int j = 0; j < 64; ++j) v[j] = prow[j * 64 + lane];
    unsigned long long rem = 0ull;      // removed mask (keeps v[] in registers)
    int* op = idxout + (size_t)(b * NPT + row) * 20;
    for (int t = 0; t < 20; ++t) {
        float bv = -3.4e38f;
        int bj = 0;
#pragma unroll
        for (int j = 0; j < 64; ++j) {
            bool ok = !((rem >> j) & 1ull);
            if (ok && v[j] > bv) { bv = v[j]; bj = j; }   // strict > keeps lowest j on tie
        }
        int gi = bj * 64 + lane;
#pragma unroll
        for (int s = 1; s < 64; s <<= 1) {
            float ov = __shfl_xor(bv, s);
            int og = __shfl_xor(gi, s);
            if (ov > bv || (ov == bv && og < gi)) { bv = ov; gi = og; }
        }
        if ((gi & 63) == lane) rem |= 1ull << (gi >> 6);
        if (lane == 0) op[t] = b * NPT + gi;    // global point id
    }
}

// ---------------- U = wA * X, T = (wB - wA) * X  (point-major out) ----------------
__global__ __launch_bounds__(256) void ut_gemm(const float* __restrict__ X,
                                               const float* __restrict__ w,
                                               float* __restrict__ U,
                                               float* __restrict__ T,
                                               int C, int O) {
    __shared__ float Xs[KC][PAD];
    __shared__ float Wa[KC][PAD];
    __shared__ float Wt[KC][PAD];
    int tid = threadIdx.x;
    int tx = tid & 15;          // point group
    int ty = tid >> 4;          // o group
    int pbase = blockIdx.x * 64;
    int obase = blockIdx.y * 64;
    int lc = tid & 15;
    int li = tid >> 4;
    float aU[4][4] = {}, aT[4][4] = {};
    for (int c0 = 0; c0 < C; c0 += KC) {
        int c = c0 + lc;
        bool inC = (c < C);
#pragma unroll
        for (int r = 0; r < 4; ++r) {
            int i = li + r * 16;
            Xs[lc][i] = inC ? X[(size_t)(pbase + i) * C + c] : 0.f;
            float wa = 0.f, wb = 0.f;
            if (inC) {
                const float* wrow = w + (size_t)(obase + i) * (2 * C);
                wa = wrow[c];
                wb = wrow[C + c];
            }
            Wa[lc][i] = wa;
            Wt[lc][i] = wb - wa;
        }
        __syncthreads();
#pragma unroll
        for (int cc = 0; cc < KC; ++cc) {
            float xv[4], wav[4], wtv[4];
#pragma unroll
            for (int i = 0; i < 4; ++i) xv[i] = Xs[cc][tx * 4 + i];
#pragma unroll
            for (int j = 0; j < 4; ++j) { wav[j] = Wa[cc][ty * 4 + j]; wtv[j] = Wt[cc][ty * 4 + j]; }
#pragma unroll
            for (int j = 0; j < 4; ++j)
#pragma unroll
                for (int i = 0; i < 4; ++i) {
                    aU[j][i] = fmaf(wav[j], xv[i], aU[j][i]);
                    aT[j][i] = fmaf(wtv[j], xv[i], aT[j][i]);
                }
        }
        __syncthreads();
    }
#pragma unroll
    for (int j = 0; j < 4; ++j)
#pragma unroll
        for (int i = 0; i < 4; ++i) {
            size_t p = pbase + tx * 4 + i;
            int o = obase + ty * 4 + j;
            U[p * O + o] = aU[j][i];
            T[p * O + o] = aT[j][i];
        }
}

// ---------------- gather neighbors, max over k, BN + LeakyReLU ----------------
__global__ __launch_bounds__(256) void gather_max(const float* __restrict__ U,
                                                  const float* __restrict__ T,
                                                  const int* __restrict__ idx,
                                                  const float* __restrict__ g,
                                                  const float* __restrict__ bb,
                                                  const float* __restrict__ rm,
                                                  const float* __restrict__ rv,
                                                  float* __restrict__ Xout, int O) {
    int ppb = 256 / O;
    int o = threadIdx.x % O;
    int lp = threadIdx.x / O;
    int p = blockIdx.x * ppb + lp;
    const int* ip = idx + (size_t)p * 20;
    float m = -3.4e38f;
#pragma unroll
    for (int k = 0; k < 20; ++k) {
        int j = ip[k];
        m = fmaxf(m, U[(size_t)j * O + o]);
    }
    float pre = m + T[(size_t)p * O + o];
    float scale = g[o] / sqrtf(rv[o] + EPS);
    float y = (pre - rm[o]) * scale + bb[o];
    y = y > 0.f ? y : 0.2f * y;
    Xout[(size_t)p * O + o] = y;
}

// ---------------- head stage 1: partial[ot][p] = sum_{o in ot-tile} wreg[o]*lrelu(bn(w5.h)) ----
__global__ __launch_bounds__(256) void head_partial(const float* __restrict__ X1,
                                                    const float* __restrict__ X2,
                                                    const float* __restrict__ X3,
                                                    const float* __restrict__ X4,
                                                    const float* __restrict__ w5,
                                                    const float* __restrict__ wreg,
                                                    const float* __restrict__ g,
                                                    const float* __restrict__ bb,
                                                    const float* __restrict__ rm,
                                                    const float* __restrict__ rv,
                                                    float* __restrict__ partial) {
    __shared__ float Hs[KC][PAD];
    __shared__ float Ws[KC][PAD];
    __shared__ float red[16][64];
    int tid = threadIdx.x;
    int tx = tid & 15;          // point group
    int ty = tid >> 4;          // o group
    int o0 = blockIdx.x * 64;   // ot tile (16 tiles)
    int p0 = blockIdx.y * 64;   // point tile (512 tiles)
    int lc = tid & 15;
    int li = tid >> 4;
    float acc[4][4] = {};
    for (int c0 = 0; c0 < 512; c0 += KC) {
        const float* src;
        int coff, Cs;
        if (c0 < 64)       { src = X1; coff = c0;       Cs = 64; }
        else if (c0 < 128) { src = X2; coff = c0 - 64;  Cs = 64; }
        else if (c0 < 256) { src = X3; coff = c0 - 128; Cs = 128; }
        else               { src = X4; coff = c0 - 256; Cs = 256; }
#pragma unroll
        for (int r = 0; r < 4; ++r) {
            int i = li + r * 16;
            Hs[lc][i] = src[(size_t)(p0 + i) * Cs + coff + lc];
            Ws[lc][i] = w5[(size_t)(o0 + i) * 512 + c0 + lc];
        }
        __syncthreads();
#pragma unroll
        for (int cc = 0; cc < KC; ++cc) {
            float h[4], wv[4];
#pragma unroll
            for (int i = 0; i < 4; ++i) h[i] = Hs[cc][tx * 4 + i];
#pragma unroll
            for (int j = 0; j < 4; ++j) wv[j] = Ws[cc][ty * 4 + j];
#pragma unroll
            for (int j = 0; j < 4; ++j)
#pragma unroll
                for (int i = 0; i < 4; ++i)
                    acc[j][i] = fmaf(wv[j], h[i], acc[j][i]);
        }
        __syncthreads();
    }
    float pacc[4] = {0.f, 0.f, 0.f, 0.f};
#pragma unroll
    for (int j = 0; j < 4; ++j) {
        int o = o0 + ty * 4 + j;
        float scale = g[o] / sqrtf(rv[o] + EPS);
        float sh_rm = rm[o], sh_b = bb[o];
        float wr = wreg[o];
#pragma unroll
        for (int i = 0; i < 4; ++i) {
            float y = (acc[j][i] - sh_rm) * scale + sh_b;
            y = y > 0.f ? y : 0.2f * y;
            pacc[i] = fmaf(wr, y, pacc[i]);
        }
    }
#pragma unroll
    for (int i = 0; i < 4; ++i) red[ty][tx * 4 + i] = pacc[i];
    __syncthreads();
    if (tid < 64) {
        float s = 0.f;
#pragma unroll
        for (int q = 0; q < 16; ++q) s += red[q][tid];
        partial[(size_t)blockIdx.x * PTS + p0 + tid] = s;
    }
}

// ---------------- head stage 2: out[p] = sum_ot partial[ot][p] ----------------
__global__ __launch_bounds__(256) void head_reduce(const float* __restrict__ partial,
                                                   float* __restrict__ out) {
    int p = blockIdx.x * 256 + threadIdx.x;
    if (p >= PTS) return;
    float s = 0.f;
#pragma unroll
    for (int q = 0; q < 16; ++q) s += partial[(size_t)q * PTS + p];
    out[p] = s;
}

extern "C" void kernel_launch(void* const* d_in, const int* in_sizes, int n_in,
                              void* d_out, int out_size, void* d_ws, size_t ws_size,
                              hipStream_t stream) {
    const float* x    = (const float*)d_in[0];
    const float* w1   = (const float*)d_in[1];
    const float* w2   = (const float*)d_in[2];
    const float* w3   = (const float*)d_in[3];
    const float* w4   = (const float*)d_in[4];
    const float* w5   = (const float*)d_in[5];
    const float* wreg = (const float*)d_in[6];
    const float* bn[5][4];   // g, b, rm, rv per block
    for (int t = 0; t < 5; ++t)
        for (int q = 0; q < 4; ++q)
            bn[t][q] = (const float*)d_in[7 + t * 4 + q];
    float* out = (float*)d_out;

    // workspace layout (bytes), peak ~131 MB (proven OK in round 3).
    // U/T alias the PD slab (PD dead after topk20, before ut_gemm).
    // partial aliases IDX (IDX dead after last gather_max).
    char* ws = (char*)d_ws;
    size_t o_x1  = 0;
    size_t o_x2  = o_x1  + (size_t)PTS * 64 * 4;    //  8 MB
    size_t o_x3  = o_x2  + (size_t)PTS * 64 * 4;    //  8 MB
    size_t o_x4  = o_x3  + (size_t)PTS * 128 * 4;   // 16 MB
    size_t o_idx = o_x4  + (size_t)PTS * 256 * 4;   // 32 MB
    size_t o_xx  = o_idx + (size_t)PTS * 20 * 4;    // 2.6 MB
    size_t o_pd  = o_xx  + (size_t)PTS * 4;         // 0.13 MB
    size_t o_u   = o_pd;                            // alias: U over PD slab
    size_t o_t   = o_u   + (size_t)PTS * 256 * 4;   // 32 MB after U
    // PD region = NPT*NPT*4 = 64 MB == U+T = 64 MB -> total ~131 MB

    float* X1 = (float*)(ws + o_x1);
    float* X2 = (float*)(ws + o_x2);
    float* X3 = (float*)(ws + o_x3);
    float* X4 = (float*)(ws + o_x4);
    int*   IDX = (int*)(ws + o_idx);
    float* XX = (float*)(ws + o_xx);
    float* PD = (float*)(ws + o_pd);
    float* U  = (float*)(ws + o_u);
    float* T  = (float*)(ws + o_t);
    float* PART = (float*)(ws + o_idx);   // 16*PTS*4 = 2 MB < IDX's 2.6 MB

    auto edge_block = [&](const float* Xin, int C, const float* w,
                          const float* const* bnp, float* Xout, int O) {
        sqnorm<<<PTS / 256, 256, 0, stream>>>(Xin, XX, C);
        for (int b = 0; b < BATCH; ++b) {
            pd_gemm<<<dim3(NPT / 64, NPT / 64), 256, 0, stream>>>(Xin, XX, PD, C, b);
            topk20<<<NPT / 4, 256, 0, stream>>>(PD, IDX, b);
        }
        ut_gemm<<<dim3(PTS / 64, O / 64), 256, 0, stream>>>(Xin, w, U, T, C, O);
        gather_max<<<PTS * O / 256, 256, 0, stream>>>(U, T, IDX,
                bnp[0], bnp[1], bnp[2], bnp[3], Xout, O);
    };

    edge_block(x,  1,   w1, bn[0], X1, 64);
    edge_block(X1, 64,  w2, bn[1], X2, 64);
    edge_block(X2, 64,  w3, bn[2], X3, 128);
    edge_block(X3, 128, w4, bn[3], X4, 256);

    head_partial<<<dim3(16, PTS / 64), 256, 0, stream>>>(X1, X2, X3, X4, w5, wreg,
            bn[4][0], bn[4][1], bn[4][2], bn[4][3], PART);
    head_reduce<<<PTS / 256, 256, 0, stream>>>(PART, out);
}

// Round 5
// 3993.641 us; speedup vs baseline: 1.5308x; 1.0159x over previous
//
#include <hip/hip_runtime.h>
#include <math.h>

// DGCNN_Reg: B=8, N=4096, k=20.
// Point-major layouts: X[p][c], U[p][o], T[p][o] with p = b*4096 + n.
// Edge conv factorized: y[o,n,k] = U[idx[n,k]][o] + T[n][o];
// BN+LeakyReLU (scale>0) commutes with max over k.
// R5: 8x8 micro-tile + float4 LDS reads for pd/head GEMMs (1 FMA/LDS-byte,
// was 0.5); pd1 streaming kernel for C=1 layer; head o-tiles 16->8.

constexpr int NPT = 4096;
constexpr int BATCH = 8;
constexpr int PTS = BATCH * NPT;   // 32768
constexpr float EPS = 1e-5f;
#define KC 16
#define PAD 68    // 64-wide tiles (ut_gemm): 68 mod 32 = 4 -> conflict-free staging
#define PADB 132  // 128-wide tiles: 132 mod 32 = 4 -> conflict-free staging

// ---------------- sum of squares per point ----------------
__global__ __launch_bounds__(256) void sqnorm(const float* __restrict__ X,
                                              float* __restrict__ xx, int C) {
    int p = blockIdx.x * 256 + threadIdx.x;
    if (p >= PTS) return;
    float s = 0.f;
    const float* row = X + (size_t)p * C;
    for (int c = 0; c < C; ++c) s = fmaf(row[c], row[c], s);
    xx[p] = s;
}

// ---------------- pd for C=1: pure streaming ----------------
// pd[n][m] = (2*x_n*x_m - xx_n) - xx_m
__global__ __launch_bounds__(256) void pd1(const float* __restrict__ X,
                                           const float* __restrict__ xx,
                                           float* __restrict__ pd, int b) {
    int tid = threadIdx.x;
    int colbase = blockIdx.x * 1024;
    int rowbase = blockIdx.y * 32;
    int p0 = b * NPT;
    int c = colbase + tid * 4;
    float4 xm = *(const float4*)&X[p0 + c];
    float4 xxm = *(const float4*)&xx[p0 + c];
    for (int r = 0; r < 32; ++r) {
        int row = rowbase + r;
        float xr = X[p0 + row];
        float xxr = xx[p0 + row];
        float4 o;
        o.x = (2.f * (xr * xm.x) - xxr) - xxm.x;
        o.y = (2.f * (xr * xm.y) - xxr) - xxm.y;
        o.z = (2.f * (xr * xm.z) - xxr) - xxm.z;
        o.w = (2.f * (xr * xm.w) - xxr) - xxm.w;
        *(float4*)&pd[(size_t)row * NPT + c] = o;
    }
}

// ---------------- pairwise "negative sq dist", 128x128 tile, 8x8/thread ----------------
// requires C % 16 == 0 (C in {64,128,256})
__global__ __launch_bounds__(256) void pd_gemm128(const float* __restrict__ X,
                                                  const float* __restrict__ xx,
                                                  float* __restrict__ pd,
                                                  int C, int b) {
    __shared__ __align__(16) float As[KC][PADB];
    __shared__ __align__(16) float Bs[KC][PADB];
    int tid = threadIdx.x;
    int tx = tid & 15;          // col group
    int ty = tid >> 4;          // row group
    int colbase = blockIdx.x * 128;
    int rowbase = blockIdx.y * 128;
    int p0 = b * NPT;
    int sc4 = (tid & 3) * 4;    // staging channel (float4)
    int spt = tid >> 2;         // staging point 0..63
    float acc[2][2][4][4] = {}; // [rh][ch][i][j]: row 64rh+4ty+i, col 64ch+4tx+j
    for (int c0 = 0; c0 < C; c0 += KC) {
#pragma unroll
        for (int h = 0; h < 2; ++h) {
            int pt = spt + h * 64;
            float4 av = *(const float4*)&X[(size_t)(p0 + rowbase + pt) * C + c0 + sc4];
            float4 bv = *(const float4*)&X[(size_t)(p0 + colbase + pt) * C + c0 + sc4];
            As[sc4 + 0][pt] = av.x; As[sc4 + 1][pt] = av.y;
            As[sc4 + 2][pt] = av.z; As[sc4 + 3][pt] = av.w;
            Bs[sc4 + 0][pt] = bv.x; Bs[sc4 + 1][pt] = bv.y;
            Bs[sc4 + 2][pt] = bv.z; Bs[sc4 + 3][pt] = bv.w;
        }
        __syncthreads();
#pragma unroll
        for (int cc = 0; cc < KC; ++cc) {
            float4 a0 = *(const float4*)&As[cc][ty * 4];
            float4 a1 = *(const float4*)&As[cc][64 + ty * 4];
            float4 b0 = *(const float4*)&Bs[cc][tx * 4];
            float4 b1 = *(const float4*)&Bs[cc][64 + tx * 4];
            float ar[2][4] = {{a0.x, a0.y, a0.z, a0.w}, {a1.x, a1.y, a1.z, a1.w}};
            float br[2][4] = {{b0.x, b0.y, b0.z, b0.w}, {b1.x, b1.y, b1.z, b1.w}};
#pragma unroll
            for (int rh = 0; rh < 2; ++rh)
#pragma unroll
                for (int i = 0; i < 4; ++i)
#pragma unroll
                    for (int ch = 0; ch < 2; ++ch)
#pragma unroll
                        for (int j = 0; j < 4; ++j)
                            acc[rh][ch][i][j] = fmaf(ar[rh][i], br[ch][j], acc[rh][ch][i][j]);
        }
        __syncthreads();
    }
#pragma unroll
    for (int rh = 0; rh < 2; ++rh)
#pragma unroll
        for (int i = 0; i < 4; ++i) {
            int r = rowbase + rh * 64 + ty * 4 + i;
            float xr = xx[p0 + r];
#pragma unroll
            for (int ch = 0; ch < 2; ++ch) {
                int m = colbase + ch * 64 + tx * 4;
                float4 o;
                o.x = 2.f * acc[rh][ch][i][0] - xr - xx[p0 + m + 0];
                o.y = 2.f * acc[rh][ch][i][1] - xr - xx[p0 + m + 1];
                o.z = 2.f * acc[rh][ch][i][2] - xr - xx[p0 + m + 2];
                o.w = 2.f * acc[rh][ch][i][3] - xr - xx[p0 + m + 3];
                *(float4*)&pd[(size_t)r * NPT + m] = o;
            }
        }
}

// ---------------- top-20 per row (stable, lower index wins ties) ----------------
__global__ __launch_bounds__(256) void topk20(const float* __restrict__ pd,
                                              int* __restrict__ idxout, int b) {
    int row = blockIdx.x * 4 + (threadIdx.x >> 6);
    int lane = threadIdx.x & 63;
    const float* prow = pd + (size_t)row * NPT;
    float v[64];
#pragma unroll
    for (int j = 0; j < 64; ++j) v[j] = prow[j * 64 + lane];
    unsigned long long rem = 0ull;
    int* op = idxout + (size_t)(b * NPT + row) * 20;
    for (int t = 0; t < 20; ++t) {
        float bv = -3.4e38f;
        int bj = 0;
#pragma unroll
        for (int j = 0; j < 64; ++j) {
            bool ok = !((rem >> j) & 1ull);
            if (ok && v[j] > bv) { bv = v[j]; bj = j; }
        }
        int gi = bj * 64 + lane;
#pragma unroll
        for (int s = 1; s < 64; s <<= 1) {
            float ov = __shfl_xor(bv, s);
            int og = __shfl_xor(gi, s);
            if (ov > bv || (ov == bv && og < gi)) { bv = ov; gi = og; }
        }
        if ((gi & 63) == lane) rem |= 1ull << (gi >> 6);
        if (lane == 0) op[t] = b * NPT + gi;
    }
}

// ---------------- U = wA * X, T = (wB - wA) * X  (point-major out) ----------------
__global__ __launch_bounds__(256) void ut_gemm(const float* __restrict__ X,
                                               const float* __restrict__ w,
                                               float* __restrict__ U,
                                               float* __restrict__ T,
                                               int C, int O) {
    __shared__ float Xs[KC][PAD];
    __shared__ float Wa[KC][PAD];
    __shared__ float Wt[KC][PAD];
    int tid = threadIdx.x;
    int tx = tid & 15;
    int ty = tid >> 4;
    int pbase = blockIdx.x * 64;
    int obase = blockIdx.y * 64;
    int lc = tid & 15;
    int li = tid >> 4;
    float aU[4][4] = {}, aT[4][4] = {};
    for (int c0 = 0; c0 < C; c0 += KC) {
        int c = c0 + lc;
        bool inC = (c < C);
#pragma unroll
        for (int r = 0; r < 4; ++r) {
            int i = li + r * 16;
            Xs[lc][i] = inC ? X[(size_t)(pbase + i) * C + c] : 0.f;
            float wa = 0.f, wb = 0.f;
            if (inC) {
                const float* wrow = w + (size_t)(obase + i) * (2 * C);
                wa = wrow[c];
                wb = wrow[C + c];
            }
            Wa[lc][i] = wa;
            Wt[lc][i] = wb - wa;
        }
        __syncthreads();
#pragma unroll
        for (int cc = 0; cc < KC; ++cc) {
            float xv[4], wav[4], wtv[4];
#pragma unroll
            for (int i = 0; i < 4; ++i) xv[i] = Xs[cc][tx * 4 + i];
#pragma unroll
            for (int j = 0; j < 4; ++j) { wav[j] = Wa[cc][ty * 4 + j]; wtv[j] = Wt[cc][ty * 4 + j]; }
#pragma unroll
            for (int j = 0; j < 4; ++j)
#pragma unroll
                for (int i = 0; i < 4; ++i) {
                    aU[j][i] = fmaf(wav[j], xv[i], aU[j][i]);
                    aT[j][i] = fmaf(wtv[j], xv[i], aT[j][i]);
                }
        }
        __syncthreads();
    }
#pragma unroll
    for (int j = 0; j < 4; ++j)
#pragma unroll
        for (int i = 0; i < 4; ++i) {
            size_t p = pbase + tx * 4 + i;
            int o = obase + ty * 4 + j;
            U[p * O + o] = aU[j][i];
            T[p * O + o] = aT[j][i];
        }
}

// ---------------- gather neighbors, max over k, BN + LeakyReLU ----------------
__global__ __launch_bounds__(256) void gather_max(const float* __restrict__ U,
                                                  const float* __restrict__ T,
                                                  const int* __restrict__ idx,
                                                  const float* __restrict__ g,
                                                  const float* __restrict__ bb,
                                                  const float* __restrict__ rm,
                                                  const float* __restrict__ rv,
                                                  float* __restrict__ Xout, int O) {
    int ppb = 256 / O;
    int o = threadIdx.x % O;
    int lp = threadIdx.x / O;
    int p = blockIdx.x * ppb + lp;
    const int* ip = idx + (size_t)p * 20;
    float m = -3.4e38f;
#pragma unroll
    for (int k = 0; k < 20; ++k) {
        int j = ip[k];
        m = fmaxf(m, U[(size_t)j * O + o]);
    }
    float pre = m + T[(size_t)p * O + o];
    float scale = g[o] / sqrtf(rv[o] + EPS);
    float y = (pre - rm[o]) * scale + bb[o];
    y = y > 0.f ? y : 0.2f * y;
    Xout[(size_t)p * O + o] = y;
}

// ---------------- head stage 1: 128 o x 128 p tile, 8x8/thread ----------------
__global__ __launch_bounds__(256) void head_partial(const float* __restrict__ X1,
                                                    const float* __restrict__ X2,
                                                    const float* __restrict__ X3,
                                                    const float* __restrict__ X4,
                                                    const float* __restrict__ w5,
                                                    const float* __restrict__ wreg,
                                                    const float* __restrict__ g,
                                                    const float* __restrict__ bb,
                                                    const float* __restrict__ rm,
                                                    const float* __restrict__ rv,
                                                    float* __restrict__ partial) {
    __shared__ __align__(16) float Ws[KC][PADB];   // A: o rows
    __shared__ __align__(16) float Hs[KC][PADB];   // B: p cols
    __shared__ float red[16][PADB];
    int tid = threadIdx.x;
    int tx = tid & 15;          // p group
    int ty = tid >> 4;          // o group
    int o0 = blockIdx.x * 128;  // 8 o-tiles
    int p0 = blockIdx.y * 128;  // 256 p-tiles
    int sc4 = (tid & 3) * 4;
    int spt = tid >> 2;
    float acc[2][2][4][4] = {}; // [rh(o)][ch(p)][i][j]
    for (int c0 = 0; c0 < 512; c0 += KC) {
        const float* src;
        int coff, Cs;
        if (c0 < 64)       { src = X1; coff = c0;       Cs = 64; }
        else if (c0 < 128) { src = X2; coff = c0 - 64;  Cs = 64; }
        else if (c0 < 256) { src = X3; coff = c0 - 128; Cs = 128; }
        else               { src = X4; coff = c0 - 256; Cs = 256; }
#pragma unroll
        for (int h = 0; h < 2; ++h) {
            int pt = spt + h * 64;
            float4 wv = *(const float4*)&w5[(size_t)(o0 + pt) * 512 + c0 + sc4];
            float4 hv = *(const float4*)&src[(size_t)(p0 + pt) * Cs + coff + sc4];
            Ws[sc4 + 0][pt] = wv.x; Ws[sc4 + 1][pt] = wv.y;
            Ws[sc4 + 2][pt] = wv.z; Ws[sc4 + 3][pt] = wv.w;
            Hs[sc4 + 0][pt] = hv.x; Hs[sc4 + 1][pt] = hv.y;
            Hs[sc4 + 2][pt] = hv.z; Hs[sc4 + 3][pt] = hv.w;
        }
        __syncthreads();
#pragma unroll
        for (int cc = 0; cc < KC; ++cc) {
            float4 a0 = *(const float4*)&Ws[cc][ty * 4];
            float4 a1 = *(const float4*)&Ws[cc][64 + ty * 4];
            float4 b0 = *(const float4*)&Hs[cc][tx * 4];
            float4 b1 = *(const float4*)&Hs[cc][64 + tx * 4];
            float ar[2][4] = {{a0.x, a0.y, a0.z, a0.w}, {a1.x, a1.y, a1.z, a1.w}};
            float br[2][4] = {{b0.x, b0.y, b0.z, b0.w}, {b1.x, b1.y, b1.z, b1.w}};
#pragma unroll
            for (int rh = 0; rh < 2; ++rh)
#pragma unroll
                for (int i = 0; i < 4; ++i)
#pragma unroll
                    for (int ch = 0; ch < 2; ++ch)
#pragma unroll
                        for (int j = 0; j < 4; ++j)
                            acc[rh][ch][i][j] = fmaf(ar[rh][i], br[ch][j], acc[rh][ch][i][j]);
        }
        __syncthreads();
    }
    // bn + lrelu + wreg-dot over this block's 128 o's
    float pacc[2][4] = {};
#pragma unroll
    for (int rh = 0; rh < 2; ++rh)
#pragma unroll
        for (int i = 0; i < 4; ++i) {
            int o = o0 + rh * 64 + ty * 4 + i;
            float scale = g[o] / sqrtf(rv[o] + EPS);
            float sm = rm[o], sb = bb[o], wr = wreg[o];
#pragma unroll
            for (int ch = 0; ch < 2; ++ch)
#pragma unroll
                for (int j = 0; j < 4; ++j) {
                    float y = (acc[rh][ch][i][j] - sm) * scale + sb;
                    y = y > 0.f ? y : 0.2f * y;
                    pacc[ch][j] = fmaf(wr, y, pacc[ch][j]);
                }
        }
#pragma unroll
    for (int ch = 0; ch < 2; ++ch)
#pragma unroll
        for (int j = 0; j < 4; ++j)
            red[ty][ch * 64 + tx * 4 + j] = pacc[ch][j];
    __syncthreads();
    if (tid < 128) {
        float s = 0.f;
#pragma unroll
        for (int q = 0; q < 16; ++q) s += red[q][tid];
        partial[(size_t)blockIdx.x * PTS + p0 + tid] = s;
    }
}

// ---------------- head stage 2: out[p] = sum over 8 o-tiles ----------------
__global__ __launch_bounds__(256) void head_reduce(const float* __restrict__ partial,
                                                   float* __restrict__ out) {
    int p = blockIdx.x * 256 + threadIdx.x;
    if (p >= PTS) return;
    float s = 0.f;
#pragma unroll
    for (int q = 0; q < 8; ++q) s += partial[(size_t)q * PTS + p];
    out[p] = s;
}

extern "C" void kernel_launch(void* const* d_in, const int* in_sizes, int n_in,
                              void* d_out, int out_size, void* d_ws, size_t ws_size,
                              hipStream_t stream) {
    const float* x    = (const float*)d_in[0];
    const float* w1   = (const float*)d_in[1];
    const float* w2   = (const float*)d_in[2];
    const float* w3   = (const float*)d_in[3];
    const float* w4   = (const float*)d_in[4];
    const float* w5   = (const float*)d_in[5];
    const float* wreg = (const float*)d_in[6];
    const float* bn[5][4];
    for (int t = 0; t < 5; ++t)
        for (int q = 0; q < 4; ++q)
            bn[t][q] = (const float*)d_in[7 + t * 4 + q];
    float* out = (float*)d_out;

    // workspace layout (bytes), peak ~131 MB (proven OK).
    char* ws = (char*)d_ws;
    size_t o_x1  = 0;
    size_t o_x2  = o_x1  + (size_t)PTS * 64 * 4;
    size_t o_x3  = o_x2  + (size_t)PTS * 64 * 4;
    size_t o_x4  = o_x3  + (size_t)PTS * 128 * 4;
    size_t o_idx = o_x4  + (size_t)PTS * 256 * 4;
    size_t o_xx  = o_idx + (size_t)PTS * 20 * 4;
    size_t o_pd  = o_xx  + (size_t)PTS * 4;
    size_t o_u   = o_pd;                            // alias: U over PD slab
    size_t o_t   = o_u   + (size_t)PTS * 256 * 4;

    float* X1 = (float*)(ws + o_x1);
    float* X2 = (float*)(ws + o_x2);
    float* X3 = (float*)(ws + o_x3);
    float* X4 = (float*)(ws + o_x4);
    int*   IDX = (int*)(ws + o_idx);
    float* XX = (float*)(ws + o_xx);
    float* PD = (float*)(ws + o_pd);
    float* U  = (float*)(ws + o_u);
    float* T  = (float*)(ws + o_t);
    float* PART = (float*)(ws + o_idx);   // 8*PTS*4 = 1 MB < IDX slab

    auto edge_block = [&](const float* Xin, int C, const float* w,
                          const float* const* bnp, float* Xout, int O) {
        sqnorm<<<PTS / 256, 256, 0, stream>>>(Xin, XX, C);
        for (int b = 0; b < BATCH; ++b) {
            if (C == 1)
                pd1<<<dim3(NPT / 1024, NPT / 32), 256, 0, stream>>>(Xin, XX, PD, b);
            else
                pd_gemm128<<<dim3(NPT / 128, NPT / 128), 256, 0, stream>>>(Xin, XX, PD, C, b);
            topk20<<<NPT / 4, 256, 0, stream>>>(PD, IDX, b);
        }
        ut_gemm<<<dim3(PTS / 64, O / 64), 256, 0, stream>>>(Xin, w, U, T, C, O);
        gather_max<<<PTS * O / 256, 256, 0, stream>>>(U, T, IDX,
                bnp[0], bnp[1], bnp[2], bnp[3], Xout, O);
    };

    edge_block(x,  1,   w1, bn[0], X1, 64);
    edge_block(X1, 64,  w2, bn[1], X2, 64);
    edge_block(X2, 64,  w3, bn[2], X3, 128);
    edge_block(X3, 128, w4, bn[3], X4, 256);

    head_partial<<<dim3(8, PTS / 128), 256, 0, stream>>>(X1, X2, X3, X4, w5, wreg,
            bn[4][0], bn[4][1], bn[4][2], bn[4][3], PART);
    head_reduce<<<PTS / 256, 256, 0, stream>>>(PART, out);
}

// Round 6
// 3050.236 us; speedup vs baseline: 2.0043x; 1.3093x over previous
//
#include <hip/hip_runtime.h>
#include <math.h>

// DGCNN_Reg: B=8, N=4096, k=20.
// Point-major layouts: X[p][c], U[p][o], T[p][o] with p = b*4096 + n.
// Edge conv factorized: y[o,n,k] = U[idx[n,k]][o] + T[n][o];
// BN+LeakyReLU (scale>0) commutes with max over k.
// R6: symmetric pd (528/1024 tiles, mirrored store, bit-identical values);
// topk via per-lane top-2 + lazy rescan (~5x fewer VALU ops);
// pd1 fully streaming (1 thread / float4).

constexpr int NPT = 4096;
constexpr int BATCH = 8;
constexpr int PTS = BATCH * NPT;   // 32768
constexpr float EPS = 1e-5f;
#define KC 16
#define PAD 68    // 64-wide tiles: 68 mod 32 = 4 -> conflict-free staging
#define PADB 132  // 128-wide tiles: 132 mod 32 = 4 -> conflict-free staging
#define NEG_INF -3.4e38f

// ---------------- sum of squares per point ----------------
__global__ __launch_bounds__(256) void sqnorm(const float* __restrict__ X,
                                              float* __restrict__ xx, int C) {
    int p = blockIdx.x * 256 + threadIdx.x;
    if (p >= PTS) return;
    float s = 0.f;
    const float* row = X + (size_t)p * C;
    for (int c = 0; c < C; ++c) s = fmaf(row[c], row[c], s);
    xx[p] = s;
}

// ---------------- pd for C=1: pure streaming, 1 thread per float4 ----------------
// pd[n][m] = (2*x_n*x_m - xx_n) - xx_m
__global__ __launch_bounds__(256) void pd1(const float* __restrict__ X,
                                           const float* __restrict__ xx,
                                           float* __restrict__ pd, int b) {
    int p = blockIdx.x * 256 + threadIdx.x;   // [0, 4096*1024)
    int row = p >> 10;
    int c = (p & 1023) * 4;
    int p0 = b * NPT;
    float xr = X[p0 + row];
    float xxr = xx[p0 + row];
    float4 xm = *(const float4*)&X[p0 + c];
    float4 xxm = *(const float4*)&xx[p0 + c];
    float4 o;
    o.x = (2.f * (xr * xm.x) - xxr) - xxm.x;
    o.y = (2.f * (xr * xm.y) - xxr) - xxm.y;
    o.z = (2.f * (xr * xm.z) - xxr) - xxm.z;
    o.w = (2.f * (xr * xm.w) - xxr) - xxm.w;
    *(float4*)&pd[(size_t)row * NPT + c] = o;
}

// ---------------- symmetric pairwise distances, 128x128 tiles, upper triangle ----
// pd is bit-symmetric (FMA chain term-commutative, same k-order), so compute
// tile pairs ti<=tj only (528 of 1024) and mirror. C in {64,128,256}.
__global__ __launch_bounds__(256) void pd_sym128(const float* __restrict__ X,
                                                 const float* __restrict__ xx,
                                                 float* __restrict__ pd,
                                                 int C, int b) {
    // triangular decode: bid -> (ti, tj), ti<=tj, 32 tiles/dim
    int bid = blockIdx.x;
    int ti = 0, rem = bid;
    while (rem >= 32 - ti) { rem -= 32 - ti; ++ti; }
    int tj = ti + rem;
    int rowbase = ti * 128, colbase = tj * 128;

    __shared__ __align__(16) float As[KC][PADB];
    __shared__ __align__(16) float Bs[KC][PADB];
    int tid = threadIdx.x;
    int tx = tid & 15;          // col group
    int ty = tid >> 4;          // row group
    int p0 = b * NPT;
    int sc4 = (tid & 3) * 4;    // staging channel (float4)
    int spt = tid >> 2;         // staging point 0..63
    float acc[2][2][4][4] = {}; // [rh][ch][i][j]: row 64rh+4ty+i, col 64ch+4tx+j
    for (int c0 = 0; c0 < C; c0 += KC) {
#pragma unroll
        for (int h = 0; h < 2; ++h) {
            int pt = spt + h * 64;
            float4 av = *(const float4*)&X[(size_t)(p0 + rowbase + pt) * C + c0 + sc4];
            float4 bv = *(const float4*)&X[(size_t)(p0 + colbase + pt) * C + c0 + sc4];
            As[sc4 + 0][pt] = av.x; As[sc4 + 1][pt] = av.y;
            As[sc4 + 2][pt] = av.z; As[sc4 + 3][pt] = av.w;
            Bs[sc4 + 0][pt] = bv.x; Bs[sc4 + 1][pt] = bv.y;
            Bs[sc4 + 2][pt] = bv.z; Bs[sc4 + 3][pt] = bv.w;
        }
        __syncthreads();
#pragma unroll
        for (int cc = 0; cc < KC; ++cc) {
            float4 a0 = *(const float4*)&As[cc][ty * 4];
            float4 a1 = *(const float4*)&As[cc][64 + ty * 4];
            float4 b0 = *(const float4*)&Bs[cc][tx * 4];
            float4 b1 = *(const float4*)&Bs[cc][64 + tx * 4];
            float ar[2][4] = {{a0.x, a0.y, a0.z, a0.w}, {a1.x, a1.y, a1.z, a1.w}};
            float br[2][4] = {{b0.x, b0.y, b0.z, b0.w}, {b1.x, b1.y, b1.z, b1.w}};
#pragma unroll
            for (int rh = 0; rh < 2; ++rh)
#pragma unroll
                for (int i = 0; i < 4; ++i)
#pragma unroll
                    for (int ch = 0; ch < 2; ++ch)
#pragma unroll
                        for (int j = 0; j < 4; ++j)
                            acc[rh][ch][i][j] = fmaf(ar[rh][i], br[ch][j], acc[rh][ch][i][j]);
        }
        __syncthreads();
    }
    float xr[2][4], xm[2][4];
#pragma unroll
    for (int rh = 0; rh < 2; ++rh)
#pragma unroll
        for (int i = 0; i < 4; ++i) xr[rh][i] = xx[p0 + rowbase + rh * 64 + ty * 4 + i];
#pragma unroll
    for (int ch = 0; ch < 2; ++ch)
#pragma unroll
        for (int j = 0; j < 4; ++j) xm[ch][j] = xx[p0 + colbase + ch * 64 + tx * 4 + j];
    // normal store: pd[r][m] = 2*acc - xx[r] - xx[m] (row-first order)
#pragma unroll
    for (int rh = 0; rh < 2; ++rh)
#pragma unroll
        for (int i = 0; i < 4; ++i) {
            int r = rowbase + rh * 64 + ty * 4 + i;
            float xrv = xr[rh][i];
#pragma unroll
            for (int ch = 0; ch < 2; ++ch) {
                int m = colbase + ch * 64 + tx * 4;
                float4 o;
                o.x = 2.f * acc[rh][ch][i][0] - xrv - xm[ch][0];
                o.y = 2.f * acc[rh][ch][i][1] - xrv - xm[ch][1];
                o.z = 2.f * acc[rh][ch][i][2] - xrv - xm[ch][2];
                o.w = 2.f * acc[rh][ch][i][3] - xrv - xm[ch][3];
                *(float4*)&pd[(size_t)r * NPT + m] = o;
            }
        }
    // mirrored store: pd[m][r] = 2*acc - xx[m] - xx[r] (row-first w.r.t. row m)
    if (ti != tj) {
#pragma unroll
        for (int ch = 0; ch < 2; ++ch)
#pragma unroll
            for (int j = 0; j < 4; ++j) {
                int m = colbase + ch * 64 + tx * 4 + j;
                float xmv = xm[ch][j];
#pragma unroll
                for (int rh = 0; rh < 2; ++rh) {
                    float4 o;
                    o.x = 2.f * acc[rh][ch][0][j] - xmv - xr[rh][0];
                    o.y = 2.f * acc[rh][ch][1][j] - xmv - xr[rh][1];
                    o.z = 2.f * acc[rh][ch][2][j] - xmv - xr[rh][2];
                    o.w = 2.f * acc[rh][ch][3][j] - xmv - xr[rh][3];
                    *(float4*)&pd[(size_t)m * NPT + rowbase + rh * 64 + ty * 4] = o;
                }
            }
    }
}

// ---------------- top-20 per row: per-lane top-2 + lazy rescan ----------------
// Same set/order/tie-breaks as lax.top_k (desc value, asc index on ties).
__global__ __launch_bounds__(256) void topk20(const float* __restrict__ pd,
                                              int* __restrict__ idxout, int b) {
    int row = blockIdx.x * 4 + (threadIdx.x >> 6);
    int lane = threadIdx.x & 63;
    const float4* prow4 = (const float4*)(pd + (size_t)row * NPT);
    float v[64];
#pragma unroll
    for (int q = 0; q < 16; ++q) {
        float4 t = prow4[q * 64 + lane];
        v[q * 4 + 0] = t.x; v[q * 4 + 1] = t.y;
        v[q * 4 + 2] = t.z; v[q * 4 + 3] = t.w;
    }
    // global col of v[j] = (j>>2)*256 + lane*4 + (j&3) -- ascending in j per lane.
    float m1 = NEG_INF, m2 = NEG_INF;
    int j1 = 0, j2 = 0;
#pragma unroll
    for (int j = 0; j < 64; ++j) {
        float vv = v[j];
        bool c1 = vv > m1;          // strict > : earlier (smaller) j wins ties
        bool c2 = vv > m2;
        m2 = c1 ? m1 : (c2 ? vv : m2);
        j2 = c1 ? j1 : (c2 ? j : j2);
        m1 = c1 ? vv : m1;
        j1 = c1 ? j : j1;
    }
    bool have2 = true;
    unsigned long long rem = 0ull;
    int* op = idxout + (size_t)(b * NPT + row) * 20;
    for (int t = 0; t < 20; ++t) {
        int g1 = ((j1 >> 2) << 8) + (lane << 2) + (j1 & 3);
        float bv = m1; int gi = g1;
#pragma unroll
        for (int s = 1; s < 64; s <<= 1) {
            float ov = __shfl_xor(bv, s);
            int og = __shfl_xor(gi, s);
            if (ov > bv || (ov == bv && og < gi)) { bv = ov; gi = og; }
        }
        if (lane == 0) op[t] = b * NPT + gi;
        bool needscan = false;
        if (gi == g1) {             // this lane's candidate won (g encodes lane)
            rem |= 1ull << j1;
            if (have2) { m1 = m2; j1 = j2; have2 = false; }
            else needscan = true;
        }
        if (__any(needscan)) {
            if (needscan) {
                m1 = NEG_INF; m2 = NEG_INF; j1 = 0; j2 = 0;
#pragma unroll
                for (int j = 0; j < 64; ++j) {
                    bool alive = !((rem >> j) & 1ull);
                    float vv = alive ? v[j] : NEG_INF;
                    bool c1 = vv > m1;
                    bool c2 = vv > m2;
                    m2 = c1 ? m1 : (c2 ? vv : m2);
                    j2 = c1 ? j1 : (c2 ? j : j2);
                    m1 = c1 ? vv : m1;
                    j1 = c1 ? j : j1;
                }
                have2 = true;
            }
        }
    }
}

// ---------------- U = wA * X, T = (wB - wA) * X  (point-major out) ----------------
__global__ __launch_bounds__(256) void ut_gemm(const float* __restrict__ X,
                                               const float* __restrict__ w,
                                               float* __restrict__ U,
                                               float* __restrict__ T,
                                               int C, int O) {
    __shared__ float Xs[KC][PAD];
    __shared__ float Wa[KC][PAD];
    __shared__ float Wt[KC][PAD];
    int tid = threadIdx.x;
    int tx = tid & 15;
    int ty = tid >> 4;
    int pbase = blockIdx.x * 64;
    int obase = blockIdx.y * 64;
    int lc = tid & 15;
    int li = tid >> 4;
    float aU[4][4] = {}, aT[4][4] = {};
    for (int c0 = 0; c0 < C; c0 += KC) {
        int c = c0 + lc;
        bool inC = (c < C);
#pragma unroll
        for (int r = 0; r < 4; ++r) {
            int i = li + r * 16;
            Xs[lc][i] = inC ? X[(size_t)(pbase + i) * C + c] : 0.f;
            float wa = 0.f, wb = 0.f;
            if (inC) {
                const float* wrow = w + (size_t)(obase + i) * (2 * C);
                wa = wrow[c];
                wb = wrow[C + c];
            }
            Wa[lc][i] = wa;
            Wt[lc][i] = wb - wa;
        }
        __syncthreads();
#pragma unroll
        for (int cc = 0; cc < KC; ++cc) {
            float xv[4], wav[4], wtv[4];
#pragma unroll
            for (int i = 0; i < 4; ++i) xv[i] = Xs[cc][tx * 4 + i];
#pragma unroll
            for (int j = 0; j < 4; ++j) { wav[j] = Wa[cc][ty * 4 + j]; wtv[j] = Wt[cc][ty * 4 + j]; }
#pragma unroll
            for (int j = 0; j < 4; ++j)
#pragma unroll
                for (int i = 0; i < 4; ++i) {
                    aU[j][i] = fmaf(wav[j], xv[i], aU[j][i]);
                    aT[j][i] = fmaf(wtv[j], xv[i], aT[j][i]);
                }
        }
        __syncthreads();
    }
#pragma unroll
    for (int j = 0; j < 4; ++j)
#pragma unroll
        for (int i = 0; i < 4; ++i) {
            size_t p = pbase + tx * 4 + i;
            int o = obase + ty * 4 + j;
            U[p * O + o] = aU[j][i];
            T[p * O + o] = aT[j][i];
        }
}

// ---------------- gather neighbors, max over k, BN + LeakyReLU ----------------
__global__ __launch_bounds__(256) void gather_max(const float* __restrict__ U,
                                                  const float* __restrict__ T,
                                                  const int* __restrict__ idx,
                                                  const float* __restrict__ g,
                                                  const float* __restrict__ bb,
                                                  const float* __restrict__ rm,
                                                  const float* __restrict__ rv,
                                                  float* __restrict__ Xout, int O) {
    int ppb = 256 / O;
    int o = threadIdx.x % O;
    int lp = threadIdx.x / O;
    int p = blockIdx.x * ppb + lp;
    const int* ip = idx + (size_t)p * 20;
    float m = NEG_INF;
#pragma unroll
    for (int k = 0; k < 20; ++k) {
        int j = ip[k];
        m = fmaxf(m, U[(size_t)j * O + o]);
    }
    float pre = m + T[(size_t)p * O + o];
    float scale = g[o] / sqrtf(rv[o] + EPS);
    float y = (pre - rm[o]) * scale + bb[o];
    y = y > 0.f ? y : 0.2f * y;
    Xout[(size_t)p * O + o] = y;
}

// ---------------- head stage 1: 128 o x 128 p tile, 8x8/thread ----------------
__global__ __launch_bounds__(256) void head_partial(const float* __restrict__ X1,
                                                    const float* __restrict__ X2,
                                                    const float* __restrict__ X3,
                                                    const float* __restrict__ X4,
                                                    const float* __restrict__ w5,
                                                    const float* __restrict__ wreg,
                                                    const float* __restrict__ g,
                                                    const float* __restrict__ bb,
                                                    const float* __restrict__ rm,
                                                    const float* __restrict__ rv,
                                                    float* __restrict__ partial) {
    __shared__ __align__(16) float Ws[KC][PADB];   // A: o rows
    __shared__ __align__(16) float Hs[KC][PADB];   // B: p cols
    __shared__ float red[16][PADB];
    int tid = threadIdx.x;
    int tx = tid & 15;          // p group
    int ty = tid >> 4;          // o group
    int o0 = blockIdx.x * 128;  // 8 o-tiles
    int p0 = blockIdx.y * 128;  // 256 p-tiles
    int sc4 = (tid & 3) * 4;
    int spt = tid >> 2;
    float acc[2][2][4][4] = {}; // [rh(o)][ch(p)][i][j]
    for (int c0 = 0; c0 < 512; c0 += KC) {
        const float* src;
        int coff, Cs;
        if (c0 < 64)       { src = X1; coff = c0;       Cs = 64; }
        else if (c0 < 128) { src = X2; coff = c0 - 64;  Cs = 64; }
        else if (c0 < 256) { src = X3; coff = c0 - 128; Cs = 128; }
        else               { src = X4; coff = c0 - 256; Cs = 256; }
#pragma unroll
        for (int h = 0; h < 2; ++h) {
            int pt = spt + h * 64;
            float4 wv = *(const float4*)&w5[(size_t)(o0 + pt) * 512 + c0 + sc4];
            float4 hv = *(const float4*)&src[(size_t)(p0 + pt) * Cs + coff + sc4];
            Ws[sc4 + 0][pt] = wv.x; Ws[sc4 + 1][pt] = wv.y;
            Ws[sc4 + 2][pt] = wv.z; Ws[sc4 + 3][pt] = wv.w;
            Hs[sc4 + 0][pt] = hv.x; Hs[sc4 + 1][pt] = hv.y;
            Hs[sc4 + 2][pt] = hv.z; Hs[sc4 + 3][pt] = hv.w;
        }
        __syncthreads();
#pragma unroll
        for (int cc = 0; cc < KC; ++cc) {
            float4 a0 = *(const float4*)&Ws[cc][ty * 4];
            float4 a1 = *(const float4*)&Ws[cc][64 + ty * 4];
            float4 b0 = *(const float4*)&Hs[cc][tx * 4];
            float4 b1 = *(const float4*)&Hs[cc][64 + tx * 4];
            float ar[2][4] = {{a0.x, a0.y, a0.z, a0.w}, {a1.x, a1.y, a1.z, a1.w}};
            float br[2][4] = {{b0.x, b0.y, b0.z, b0.w}, {b1.x, b1.y, b1.z, b1.w}};
#pragma unroll
            for (int rh = 0; rh < 2; ++rh)
#pragma unroll
                for (int i = 0; i < 4; ++i)
#pragma unroll
                    for (int ch = 0; ch < 2; ++ch)
#pragma unroll
                        for (int j = 0; j < 4; ++j)
                            acc[rh][ch][i][j] = fmaf(ar[rh][i], br[ch][j], acc[rh][ch][i][j]);
        }
        __syncthreads();
    }
    float pacc[2][4] = {};
#pragma unroll
    for (int rh = 0; rh < 2; ++rh)
#pragma unroll
        for (int i = 0; i < 4; ++i) {
            int o = o0 + rh * 64 + ty * 4 + i;
            float scale = g[o] / sqrtf(rv[o] + EPS);
            float sm = rm[o], sb = bb[o], wr = wreg[o];
#pragma unroll
            for (int ch = 0; ch < 2; ++ch)
#pragma unroll
                for (int j = 0; j < 4; ++j) {
                    float y = (acc[rh][ch][i][j] - sm) * scale + sb;
                    y = y > 0.f ? y : 0.2f * y;
                    pacc[ch][j] = fmaf(wr, y, pacc[ch][j]);
                }
        }
#pragma unroll
    for (int ch = 0; ch < 2; ++ch)
#pragma unroll
        for (int j = 0; j < 4; ++j)
            red[ty][ch * 64 + tx * 4 + j] = pacc[ch][j];
    __syncthreads();
    if (tid < 128) {
        float s = 0.f;
#pragma unroll
        for (int q = 0; q < 16; ++q) s += red[q][tid];
        partial[(size_t)blockIdx.x * PTS + p0 + tid] = s;
    }
}

// ---------------- head stage 2: out[p] = sum over 8 o-tiles ----------------
__global__ __launch_bounds__(256) void head_reduce(const float* __restrict__ partial,
                                                   float* __restrict__ out) {
    int p = blockIdx.x * 256 + threadIdx.x;
    if (p >= PTS) return;
    float s = 0.f;
#pragma unroll
    for (int q = 0; q < 8; ++q) s += partial[(size_t)q * PTS + p];
    out[p] = s;
}

extern "C" void kernel_launch(void* const* d_in, const int* in_sizes, int n_in,
                              void* d_out, int out_size, void* d_ws, size_t ws_size,
                              hipStream_t stream) {
    const float* x    = (const float*)d_in[0];
    const float* w1   = (const float*)d_in[1];
    const float* w2   = (const float*)d_in[2];
    const float* w3   = (const float*)d_in[3];
    const float* w4   = (const float*)d_in[4];
    const float* w5   = (const float*)d_in[5];
    const float* wreg = (const float*)d_in[6];
    const float* bn[5][4];
    for (int t = 0; t < 5; ++t)
        for (int q = 0; q < 4; ++q)
            bn[t][q] = (const float*)d_in[7 + t * 4 + q];
    float* out = (float*)d_out;

    // workspace layout (bytes), peak ~131 MB (proven OK).
    char* ws = (char*)d_ws;
    size_t o_x1  = 0;
    size_t o_x2  = o_x1  + (size_t)PTS * 64 * 4;
    size_t o_x3  = o_x2  + (size_t)PTS * 64 * 4;
    size_t o_x4  = o_x3  + (size_t)PTS * 128 * 4;
    size_t o_idx = o_x4  + (size_t)PTS * 256 * 4;
    size_t o_xx  = o_idx + (size_t)PTS * 20 * 4;
    size_t o_pd  = o_xx  + (size_t)PTS * 4;
    size_t o_u   = o_pd;                            // alias: U over PD slab
    size_t o_t   = o_u   + (size_t)PTS * 256 * 4;

    float* X1 = (float*)(ws + o_x1);
    float* X2 = (float*)(ws + o_x2);
    float* X3 = (float*)(ws + o_x3);
    float* X4 = (float*)(ws + o_x4);
    int*   IDX = (int*)(ws + o_idx);
    float* XX = (float*)(ws + o_xx);
    float* PD = (float*)(ws + o_pd);
    float* U  = (float*)(ws + o_u);
    float* T  = (float*)(ws + o_t);
    float* PART = (float*)(ws + o_idx);   // 8*PTS*4 = 1 MB < IDX slab

    auto edge_block = [&](const float* Xin, int C, const float* w,
                          const float* const* bnp, float* Xout, int O) {
        sqnorm<<<PTS / 256, 256, 0, stream>>>(Xin, XX, C);
        for (int b = 0; b < BATCH; ++b) {
            if (C == 1)
                pd1<<<NPT * (NPT / 4) / 256, 256, 0, stream>>>(Xin, XX, PD, b);
            else
                pd_sym128<<<528, 256, 0, stream>>>(Xin, XX, PD, C, b);
            topk20<<<NPT / 4, 256, 0, stream>>>(PD, IDX, b);
        }
        ut_gemm<<<dim3(PTS / 64, O / 64), 256, 0, stream>>>(Xin, w, U, T, C, O);
        gather_max<<<PTS * O / 256, 256, 0, stream>>>(U, T, IDX,
                bnp[0], bnp[1], bnp[2], bnp[3], Xout, O);
    };

    edge_block(x,  1,   w1, bn[0], X1, 64);
    edge_block(X1, 64,  w2, bn[1], X2, 64);
    edge_block(X2, 64,  w3, bn[2], X3, 128);
    edge_block(X3, 128, w4, bn[3], X4, 256);

    head_partial<<<dim3(8, PTS / 128), 256, 0, stream>>>(X1, X2, X3, X4, w5, wreg,
            bn[4][0], bn[4][1], bn[4][2], bn[4][3], PART);
    head_reduce<<<PTS / 256, 256, 0, stream>>>(PART, out);
}

// Round 7
// 2856.662 us; speedup vs baseline: 2.1401x; 1.0678x over previous
//
#include <hip/hip_runtime.h>
#include <math.h>

// DGCNN_Reg: B=8, N=4096, k=20.
// Point-major layouts: X[p][c], U[p][o], T[p][o] with p = b*4096 + n.
// Edge conv factorized: y[o,n,k] = U[idx[n,k]][o] + T[n][o];
// BN+LeakyReLU (scale>0) commutes with max over k.
// R7: double-buffered LDS in pd_sym128/head_partial (1 barrier per K-step,
// loads issued before compute); layer-1 pd fused into topk1 (no PD for C=1).

constexpr int NPT = 4096;
constexpr int BATCH = 8;
constexpr int PTS = BATCH * NPT;   // 32768
constexpr float EPS = 1e-5f;
#define KC 16
#define PAD 68    // 64-wide tiles: 68 mod 32 = 4 -> conflict-free staging
#define PADB 132  // 128-wide tiles: 132 mod 32 = 4 -> conflict-free staging
#define NEG_INF -3.4e38f

// ---------------- sum of squares per point ----------------
__global__ __launch_bounds__(256) void sqnorm(const float* __restrict__ X,
                                              float* __restrict__ xx, int C) {
    int p = blockIdx.x * 256 + threadIdx.x;
    if (p >= PTS) return;
    float s = 0.f;
    const float* row = X + (size_t)p * C;
    for (int c = 0; c < C; ++c) s = fmaf(row[c], row[c], s);
    xx[p] = s;
}

// ---------------- symmetric pairwise distances, 128x128 tiles, upper triangle ----
// Double-buffered LDS. pd bit-symmetric -> compute ti<=tj (528 tiles), mirror.
__global__ __launch_bounds__(256) void pd_sym128(const float* __restrict__ X,
                                                 const float* __restrict__ xx,
                                                 float* __restrict__ pd,
                                                 int C, int b) {
    int bid = blockIdx.x;
    int ti = 0, rem = bid;
    while (rem >= 32 - ti) { rem -= 32 - ti; ++ti; }
    int tj = ti + rem;
    int rowbase = ti * 128, colbase = tj * 128;

    __shared__ __align__(16) float As[2][KC][PADB];
    __shared__ __align__(16) float Bs[2][KC][PADB];
    int tid = threadIdx.x;
    int tx = tid & 15;          // col group
    int ty = tid >> 4;          // row group
    int p0 = b * NPT;
    int sc4 = (tid & 3) * 4;    // staging channel (float4)
    int spt = tid >> 2;         // staging point 0..63

    auto stage = [&](int s, int c0) {
#pragma unroll
        for (int h = 0; h < 2; ++h) {
            int pt = spt + h * 64;
            float4 av = *(const float4*)&X[(size_t)(p0 + rowbase + pt) * C + c0 + sc4];
            float4 bv = *(const float4*)&X[(size_t)(p0 + colbase + pt) * C + c0 + sc4];
            As[s][sc4 + 0][pt] = av.x; As[s][sc4 + 1][pt] = av.y;
            As[s][sc4 + 2][pt] = av.z; As[s][sc4 + 3][pt] = av.w;
            Bs[s][sc4 + 0][pt] = bv.x; Bs[s][sc4 + 1][pt] = bv.y;
            Bs[s][sc4 + 2][pt] = bv.z; Bs[s][sc4 + 3][pt] = bv.w;
        }
    };

    float acc[2][2][4][4] = {}; // [rh][ch][i][j]: row 64rh+4ty+i, col 64ch+4tx+j
    int nIter = C / KC;
    stage(0, 0);
    __syncthreads();
    for (int it = 0; it < nIter; ++it) {
        int cur = it & 1;
        if (it + 1 < nIter) stage(cur ^ 1, (it + 1) * KC);
        float (*A)[PADB] = As[cur];
        float (*Bp)[PADB] = Bs[cur];
#pragma unroll
        for (int cc = 0; cc < KC; ++cc) {
            float4 a0 = *(const float4*)&A[cc][ty * 4];
            float4 a1 = *(const float4*)&A[cc][64 + ty * 4];
            float4 b0 = *(const float4*)&Bp[cc][tx * 4];
            float4 b1 = *(const float4*)&Bp[cc][64 + tx * 4];
            float ar[2][4] = {{a0.x, a0.y, a0.z, a0.w}, {a1.x, a1.y, a1.z, a1.w}};
            float br[2][4] = {{b0.x, b0.y, b0.z, b0.w}, {b1.x, b1.y, b1.z, b1.w}};
#pragma unroll
            for (int rh = 0; rh < 2; ++rh)
#pragma unroll
                for (int i = 0; i < 4; ++i)
#pragma unroll
                    for (int ch = 0; ch < 2; ++ch)
#pragma unroll
                        for (int j = 0; j < 4; ++j)
                            acc[rh][ch][i][j] = fmaf(ar[rh][i], br[ch][j], acc[rh][ch][i][j]);
        }
        __syncthreads();
    }
    float xr[2][4], xm[2][4];
#pragma unroll
    for (int rh = 0; rh < 2; ++rh)
#pragma unroll
        for (int i = 0; i < 4; ++i) xr[rh][i] = xx[p0 + rowbase + rh * 64 + ty * 4 + i];
#pragma unroll
    for (int ch = 0; ch < 2; ++ch)
#pragma unroll
        for (int j = 0; j < 4; ++j) xm[ch][j] = xx[p0 + colbase + ch * 64 + tx * 4 + j];
    // normal store: pd[r][m] = 2*acc - xx[r] - xx[m]
#pragma unroll
    for (int rh = 0; rh < 2; ++rh)
#pragma unroll
        for (int i = 0; i < 4; ++i) {
            int r = rowbase + rh * 64 + ty * 4 + i;
            float xrv = xr[rh][i];
#pragma unroll
            for (int ch = 0; ch < 2; ++ch) {
                int m = colbase + ch * 64 + tx * 4;
                float4 o;
                o.x = 2.f * acc[rh][ch][i][0] - xrv - xm[ch][0];
                o.y = 2.f * acc[rh][ch][i][1] - xrv - xm[ch][1];
                o.z = 2.f * acc[rh][ch][i][2] - xrv - xm[ch][2];
                o.w = 2.f * acc[rh][ch][i][3] - xrv - xm[ch][3];
                *(float4*)&pd[(size_t)r * NPT + m] = o;
            }
        }
    // mirrored store: pd[m][r] = 2*acc - xx[m] - xx[r]
    if (ti != tj) {
#pragma unroll
        for (int ch = 0; ch < 2; ++ch)
#pragma unroll
            for (int j = 0; j < 4; ++j) {
                int m = colbase + ch * 64 + tx * 4 + j;
                float xmv = xm[ch][j];
#pragma unroll
                for (int rh = 0; rh < 2; ++rh) {
                    float4 o;
                    o.x = 2.f * acc[rh][ch][0][j] - xmv - xr[rh][0];
                    o.y = 2.f * acc[rh][ch][1][j] - xmv - xr[rh][1];
                    o.z = 2.f * acc[rh][ch][2][j] - xmv - xr[rh][2];
                    o.w = 2.f * acc[rh][ch][3][j] - xmv - xr[rh][3];
                    *(float4*)&pd[(size_t)m * NPT + rowbase + rh * 64 + ty * 4] = o;
                }
            }
    }
}

// ---------------- shared topk core: per-lane top-2 + lazy rescan ----------------
// v[64] per lane; global col of v[j] = (j>>2)*256 + lane*4 + (j&3).
__device__ __forceinline__ void topk_core(float (&v)[64], int lane, int b,
                                          int* __restrict__ op) {
    float m1 = NEG_INF, m2 = NEG_INF;
    int j1 = 0, j2 = 0;
#pragma unroll
    for (int j = 0; j < 64; ++j) {
        float vv = v[j];
        bool c1 = vv > m1;          // strict > : earlier (smaller) j wins ties
        bool c2 = vv > m2;
        m2 = c1 ? m1 : (c2 ? vv : m2);
        j2 = c1 ? j1 : (c2 ? j : j2);
        m1 = c1 ? vv : m1;
        j1 = c1 ? j : j1;
    }
    bool have2 = true;
    unsigned long long remM = 0ull;
    for (int t = 0; t < 20; ++t) {
        int g1 = ((j1 >> 2) << 8) + (lane << 2) + (j1 & 3);
        float bv = m1; int gi = g1;
#pragma unroll
        for (int s = 1; s < 64; s <<= 1) {
            float ov = __shfl_xor(bv, s);
            int og = __shfl_xor(gi, s);
            if (ov > bv || (ov == bv && og < gi)) { bv = ov; gi = og; }
        }
        if (lane == 0) op[t] = b * NPT + gi;
        bool needscan = false;
        if (gi == g1) {             // this lane's candidate won
            remM |= 1ull << j1;
            if (have2) { m1 = m2; j1 = j2; have2 = false; }
            else needscan = true;
        }
        if (__any(needscan)) {
            if (needscan) {
                m1 = NEG_INF; m2 = NEG_INF; j1 = 0; j2 = 0;
#pragma unroll
                for (int j = 0; j < 64; ++j) {
                    bool alive = !((remM >> j) & 1ull);
                    float vv = alive ? v[j] : NEG_INF;
                    bool c1 = vv > m1;
                    bool c2 = vv > m2;
                    m2 = c1 ? m1 : (c2 ? vv : m2);
                    j2 = c1 ? j1 : (c2 ? j : j2);
                    m1 = c1 ? vv : m1;
                    j1 = c1 ? j : j1;
                }
                have2 = true;
            }
        }
    }
}

// ---------------- top-20 from materialized pd ----------------
__global__ __launch_bounds__(256) void topk20(const float* __restrict__ pd,
                                              int* __restrict__ idxout, int b) {
    int row = blockIdx.x * 4 + (threadIdx.x >> 6);
    int lane = threadIdx.x & 63;
    const float4* prow4 = (const float4*)(pd + (size_t)row * NPT);
    float v[64];
#pragma unroll
    for (int q = 0; q < 16; ++q) {
        float4 t = prow4[q * 64 + lane];
        v[q * 4 + 0] = t.x; v[q * 4 + 1] = t.y;
        v[q * 4 + 2] = t.z; v[q * 4 + 3] = t.w;
    }
    topk_core(v, lane, b, idxout + (size_t)(b * NPT + row) * 20);
}

// ---------------- layer-1 (C=1) fused pd+topk: pd computed inline ----------------
__global__ __launch_bounds__(256) void topk1(const float* __restrict__ X,
                                             const float* __restrict__ xx,
                                             int* __restrict__ idxout) {
    int b = blockIdx.y;
    int row = blockIdx.x * 4 + (threadIdx.x >> 6);
    int lane = threadIdx.x & 63;
    int p0 = b * NPT;
    float xr = X[p0 + row];
    float xxr = xx[p0 + row];
    const float4* xb4 = (const float4*)(X + p0);
    const float4* xxb4 = (const float4*)(xx + p0);
    float v[64];
#pragma unroll
    for (int q = 0; q < 16; ++q) {
        float4 xm = xb4[q * 64 + lane];
        float4 xxm = xxb4[q * 64 + lane];
        v[q * 4 + 0] = (2.f * (xr * xm.x) - xxr) - xxm.x;
        v[q * 4 + 1] = (2.f * (xr * xm.y) - xxr) - xxm.y;
        v[q * 4 + 2] = (2.f * (xr * xm.z) - xxr) - xxm.z;
        v[q * 4 + 3] = (2.f * (xr * xm.w) - xxr) - xxm.w;
    }
    topk_core(v, lane, b, idxout + (size_t)(b * NPT + row) * 20);
}

// ---------------- U = wA * X, T = (wB - wA) * X  (point-major out) ----------------
__global__ __launch_bounds__(256) void ut_gemm(const float* __restrict__ X,
                                               const float* __restrict__ w,
                                               float* __restrict__ U,
                                               float* __restrict__ T,
                                               int C, int O) {
    __shared__ float Xs[KC][PAD];
    __shared__ float Wa[KC][PAD];
    __shared__ float Wt[KC][PAD];
    int tid = threadIdx.x;
    int tx = tid & 15;
    int ty = tid >> 4;
    int pbase = blockIdx.x * 64;
    int obase = blockIdx.y * 64;
    int lc = tid & 15;
    int li = tid >> 4;
    float aU[4][4] = {}, aT[4][4] = {};
    for (int c0 = 0; c0 < C; c0 += KC) {
        int c = c0 + lc;
        bool inC = (c < C);
#pragma unroll
        for (int r = 0; r < 4; ++r) {
            int i = li + r * 16;
            Xs[lc][i] = inC ? X[(size_t)(pbase + i) * C + c] : 0.f;
            float wa = 0.f, wb = 0.f;
            if (inC) {
                const float* wrow = w + (size_t)(obase + i) * (2 * C);
                wa = wrow[c];
                wb = wrow[C + c];
            }
            Wa[lc][i] = wa;
            Wt[lc][i] = wb - wa;
        }
        __syncthreads();
#pragma unroll
        for (int cc = 0; cc < KC; ++cc) {
            float xv[4], wav[4], wtv[4];
#pragma unroll
            for (int i = 0; i < 4; ++i) xv[i] = Xs[cc][tx * 4 + i];
#pragma unroll
            for (int j = 0; j < 4; ++j) { wav[j] = Wa[cc][ty * 4 + j]; wtv[j] = Wt[cc][ty * 4 + j]; }
#pragma unroll
            for (int j = 0; j < 4; ++j)
#pragma unroll
                for (int i = 0; i < 4; ++i) {
                    aU[j][i] = fmaf(wav[j], xv[i], aU[j][i]);
                    aT[j][i] = fmaf(wtv[j], xv[i], aT[j][i]);
                }
        }
        __syncthreads();
    }
#pragma unroll
    for (int j = 0; j < 4; ++j)
#pragma unroll
        for (int i = 0; i < 4; ++i) {
            size_t p = pbase + tx * 4 + i;
            int o = obase + ty * 4 + j;
            U[p * O + o] = aU[j][i];
            T[p * O + o] = aT[j][i];
        }
}

// ---------------- gather neighbors, max over k, BN + LeakyReLU ----------------
__global__ __launch_bounds__(256) void gather_max(const float* __restrict__ U,
                                                  const float* __restrict__ T,
                                                  const int* __restrict__ idx,
                                                  const float* __restrict__ g,
                                                  const float* __restrict__ bb,
                                                  const float* __restrict__ rm,
                                                  const float* __restrict__ rv,
                                                  float* __restrict__ Xout, int O) {
    int ppb = 256 / O;
    int o = threadIdx.x % O;
    int lp = threadIdx.x / O;
    int p = blockIdx.x * ppb + lp;
    const int* ip = idx + (size_t)p * 20;
    float m = NEG_INF;
#pragma unroll
    for (int k = 0; k < 20; ++k) {
        int j = ip[k];
        m = fmaxf(m, U[(size_t)j * O + o]);
    }
    float pre = m + T[(size_t)p * O + o];
    float scale = g[o] / sqrtf(rv[o] + EPS);
    float y = (pre - rm[o]) * scale + bb[o];
    y = y > 0.f ? y : 0.2f * y;
    Xout[(size_t)p * O + o] = y;
}

// ---------------- head stage 1: 128 o x 128 p tile, 8x8/thread, dbuf ----------------
__global__ __launch_bounds__(256) void head_partial(const float* __restrict__ X1,
                                                    const float* __restrict__ X2,
                                                    const float* __restrict__ X3,
                                                    const float* __restrict__ X4,
                                                    const float* __restrict__ w5,
                                                    const float* __restrict__ wreg,
                                                    const float* __restrict__ g,
                                                    const float* __restrict__ bb,
                                                    const float* __restrict__ rm,
                                                    const float* __restrict__ rv,
                                                    float* __restrict__ partial) {
    __shared__ __align__(16) float Ws[2][KC][PADB];   // A: o rows
    __shared__ __align__(16) float Hs[2][KC][PADB];   // B: p cols
    __shared__ float red[16][PADB];
    int tid = threadIdx.x;
    int tx = tid & 15;          // p group
    int ty = tid >> 4;          // o group
    int o0 = blockIdx.x * 128;  // 8 o-tiles
    int p0 = blockIdx.y * 128;  // 256 p-tiles
    int sc4 = (tid & 3) * 4;
    int spt = tid >> 2;

    auto stage = [&](int s, int c0) {
        const float* src;
        int coff, Cs;
        if (c0 < 64)       { src = X1; coff = c0;       Cs = 64; }
        else if (c0 < 128) { src = X2; coff = c0 - 64;  Cs = 64; }
        else if (c0 < 256) { src = X3; coff = c0 - 128; Cs = 128; }
        else               { src = X4; coff = c0 - 256; Cs = 256; }
#pragma unroll
        for (int h = 0; h < 2; ++h) {
            int pt = spt + h * 64;
            float4 wv = *(const float4*)&w5[(size_t)(o0 + pt) * 512 + c0 + sc4];
            float4 hv = *(const float4*)&src[(size_t)(p0 + pt) * Cs + coff + sc4];
            Ws[s][sc4 + 0][pt] = wv.x; Ws[s][sc4 + 1][pt] = wv.y;
            Ws[s][sc4 + 2][pt] = wv.z; Ws[s][sc4 + 3][pt] = wv.w;
            Hs[s][sc4 + 0][pt] = hv.x; Hs[s][sc4 + 1][pt] = hv.y;
            Hs[s][sc4 + 2][pt] = hv.z; Hs[s][sc4 + 3][pt] = hv.w;
        }
    };

    float acc[2][2][4][4] = {}; // [rh(o)][ch(p)][i][j]
    stage(0, 0);
    __syncthreads();
    for (int it = 0; it < 32; ++it) {
        int cur = it & 1;
        if (it + 1 < 32) stage(cur ^ 1, (it + 1) * KC);
        float (*A)[PADB] = Ws[cur];
        float (*Bp)[PADB] = Hs[cur];
#pragma unroll
        for (int cc = 0; cc < KC; ++cc) {
            float4 a0 = *(const float4*)&A[cc][ty * 4];
            float4 a1 = *(const float4*)&A[cc][64 + ty * 4];
            float4 b0 = *(const float4*)&Bp[cc][tx * 4];
            float4 b1 = *(const float4*)&Bp[cc][64 + tx * 4];
            float ar[2][4] = {{a0.x, a0.y, a0.z, a0.w}, {a1.x, a1.y, a1.z, a1.w}};
            float br[2][4] = {{b0.x, b0.y, b0.z, b0.w}, {b1.x, b1.y, b1.z, b1.w}};
#pragma unroll
            for (int rh = 0; rh < 2; ++rh)
#pragma unroll
                for (int i = 0; i < 4; ++i)
#pragma unroll
                    for (int ch = 0; ch < 2; ++ch)
#pragma unroll
                        for (int j = 0; j < 4; ++j)
                            acc[rh][ch][i][j] = fmaf(ar[rh][i], br[ch][j], acc[rh][ch][i][j]);
        }
        __syncthreads();
    }
    float pacc[2][4] = {};
#pragma unroll
    for (int rh = 0; rh < 2; ++rh)
#pragma unroll
        for (int i = 0; i < 4; ++i) {
            int o = o0 + rh * 64 + ty * 4 + i;
            float scale = g[o] / sqrtf(rv[o] + EPS);
            float sm = rm[o], sb = bb[o], wr = wreg[o];
#pragma unroll
            for (int ch = 0; ch < 2; ++ch)
#pragma unroll
                for (int j = 0; j < 4; ++j) {
                    float y = (acc[rh][ch][i][j] - sm) * scale + sb;
                    y = y > 0.f ? y : 0.2f * y;
                    pacc[ch][j] = fmaf(wr, y, pacc[ch][j]);
                }
        }
#pragma unroll
    for (int ch = 0; ch < 2; ++ch)
#pragma unroll
        for (int j = 0; j < 4; ++j)
            red[ty][ch * 64 + tx * 4 + j] = pacc[ch][j];
    __syncthreads();
    if (tid < 128) {
        float s = 0.f;
#pragma unroll
        for (int q = 0; q < 16; ++q) s += red[q][tid];
        partial[(size_t)blockIdx.x * PTS + p0 + tid] = s;
    }
}

// ---------------- head stage 2: out[p] = sum over 8 o-tiles ----------------
__global__ __launch_bounds__(256) void head_reduce(const float* __restrict__ partial,
                                                   float* __restrict__ out) {
    int p = blockIdx.x * 256 + threadIdx.x;
    if (p >= PTS) return;
    float s = 0.f;
#pragma unroll
    for (int q = 0; q < 8; ++q) s += partial[(size_t)q * PTS + p];
    out[p] = s;
}

extern "C" void kernel_launch(void* const* d_in, const int* in_sizes, int n_in,
                              void* d_out, int out_size, void* d_ws, size_t ws_size,
                              hipStream_t stream) {
    const float* x    = (const float*)d_in[0];
    const float* w1   = (const float*)d_in[1];
    const float* w2   = (const float*)d_in[2];
    const float* w3   = (const float*)d_in[3];
    const float* w4   = (const float*)d_in[4];
    const float* w5   = (const float*)d_in[5];
    const float* wreg = (const float*)d_in[6];
    const float* bn[5][4];
    for (int t = 0; t < 5; ++t)
        for (int q = 0; q < 4; ++q)
            bn[t][q] = (const float*)d_in[7 + t * 4 + q];
    float* out = (float*)d_out;

    // workspace layout (bytes), peak ~131 MB (proven OK).
    char* ws = (char*)d_ws;
    size_t o_x1  = 0;
    size_t o_x2  = o_x1  + (size_t)PTS * 64 * 4;
    size_t o_x3  = o_x2  + (size_t)PTS * 64 * 4;
    size_t o_x4  = o_x3  + (size_t)PTS * 128 * 4;
    size_t o_idx = o_x4  + (size_t)PTS * 256 * 4;
    size_t o_xx  = o_idx + (size_t)PTS * 20 * 4;
    size_t o_pd  = o_xx  + (size_t)PTS * 4;
    size_t o_u   = o_pd;                            // alias: U over PD slab
    size_t o_t   = o_u   + (size_t)PTS * 256 * 4;

    float* X1 = (float*)(ws + o_x1);
    float* X2 = (float*)(ws + o_x2);
    float* X3 = (float*)(ws + o_x3);
    float* X4 = (float*)(ws + o_x4);
    int*   IDX = (int*)(ws + o_idx);
    float* XX = (float*)(ws + o_xx);
    float* PD = (float*)(ws + o_pd);
    float* U  = (float*)(ws + o_u);
    float* T  = (float*)(ws + o_t);
    float* PART = (float*)(ws + o_idx);   // 8*PTS*4 = 1 MB < IDX slab

    auto edge_block = [&](const float* Xin, int C, const float* w,
                          const float* const* bnp, float* Xout, int O) {
        sqnorm<<<PTS / 256, 256, 0, stream>>>(Xin, XX, C);
        if (C == 1) {
            topk1<<<dim3(NPT / 4, BATCH), 256, 0, stream>>>(Xin, XX, IDX);
        } else {
            for (int b = 0; b < BATCH; ++b) {
                pd_sym128<<<528, 256, 0, stream>>>(Xin, XX, PD, C, b);
                topk20<<<NPT / 4, 256, 0, stream>>>(PD, IDX, b);
            }
        }
        ut_gemm<<<dim3(PTS / 64, O / 64), 256, 0, stream>>>(Xin, w, U, T, C, O);
        gather_max<<<PTS * O / 256, 256, 0, stream>>>(U, T, IDX,
                bnp[0], bnp[1], bnp[2], bnp[3], Xout, O);
    };

    edge_block(x,  1,   w1, bn[0], X1, 64);
    edge_block(X1, 64,  w2, bn[1], X2, 64);
    edge_block(X2, 64,  w3, bn[2], X3, 128);
    edge_block(X3, 128, w4, bn[3], X4, 256);

    head_partial<<<dim3(8, PTS / 128), 256, 0, stream>>>(X1, X2, X3, X4, w5, wreg,
            bn[4][0], bn[4][1], bn[4][2], bn[4][3], PART);
    head_reduce<<<PTS / 256, 256, 0, stream>>>(PART, out);
}

// Round 8
// 2824.040 us; speedup vs baseline: 2.1648x; 1.0116x over previous
//
#include <hip/hip_runtime.h>
#include <math.h>

// DGCNN_Reg: B=8, N=4096, k=20.
// Point-major layouts: X[p][c], U[p][o], T[p][o] with p = b*4096 + n.
// Edge conv factorized: y[o,n,k] = U[idx[n,k]][o] + T[n][o];
// BN+LeakyReLU (scale>0) commutes with max over k.
// R8: revert R7's LDS double-buffer (it cut occupancy 30->21%, VALUBusy 75->64%;
// single-buffer + implicit wave overlap is faster). Keep topk1 fusion.
// New: ut1 streaming kernel for C=1 (outer product); gather_max float4 over o.

constexpr int NPT = 4096;
constexpr int BATCH = 8;
constexpr int PTS = BATCH * NPT;   // 32768
constexpr float EPS = 1e-5f;
#define KC 16
#define PAD 68    // 64-wide tiles: 68 mod 32 = 4 -> conflict-free staging
#define PADB 132  // 128-wide tiles: 132 mod 32 = 4 -> conflict-free staging
#define NEG_INF -3.4e38f

// ---------------- sum of squares per point ----------------
__global__ __launch_bounds__(256) void sqnorm(const float* __restrict__ X,
                                              float* __restrict__ xx, int C) {
    int p = blockIdx.x * 256 + threadIdx.x;
    if (p >= PTS) return;
    float s = 0.f;
    const float* row = X + (size_t)p * C;
    for (int c = 0; c < C; ++c) s = fmaf(row[c], row[c], s);
    xx[p] = s;
}

// ---------------- symmetric pairwise distances, 128x128 tiles, upper triangle ----
// Single-buffer LDS (R6 form). pd bit-symmetric -> compute ti<=tj (528), mirror.
__global__ __launch_bounds__(256) void pd_sym128(const float* __restrict__ X,
                                                 const float* __restrict__ xx,
                                                 float* __restrict__ pd,
                                                 int C, int b) {
    int bid = blockIdx.x;
    int ti = 0, rem = bid;
    while (rem >= 32 - ti) { rem -= 32 - ti; ++ti; }
    int tj = ti + rem;
    int rowbase = ti * 128, colbase = tj * 128;

    __shared__ __align__(16) float As[KC][PADB];
    __shared__ __align__(16) float Bs[KC][PADB];
    int tid = threadIdx.x;
    int tx = tid & 15;          // col group
    int ty = tid >> 4;          // row group
    int p0 = b * NPT;
    int sc4 = (tid & 3) * 4;    // staging channel (float4)
    int spt = tid >> 2;         // staging point 0..63
    float acc[2][2][4][4] = {}; // [rh][ch][i][j]: row 64rh+4ty+i, col 64ch+4tx+j
    for (int c0 = 0; c0 < C; c0 += KC) {
#pragma unroll
        for (int h = 0; h < 2; ++h) {
            int pt = spt + h * 64;
            float4 av = *(const float4*)&X[(size_t)(p0 + rowbase + pt) * C + c0 + sc4];
            float4 bv = *(const float4*)&X[(size_t)(p0 + colbase + pt) * C + c0 + sc4];
            As[sc4 + 0][pt] = av.x; As[sc4 + 1][pt] = av.y;
            As[sc4 + 2][pt] = av.z; As[sc4 + 3][pt] = av.w;
            Bs[sc4 + 0][pt] = bv.x; Bs[sc4 + 1][pt] = bv.y;
            Bs[sc4 + 2][pt] = bv.z; Bs[sc4 + 3][pt] = bv.w;
        }
        __syncthreads();
#pragma unroll
        for (int cc = 0; cc < KC; ++cc) {
            float4 a0 = *(const float4*)&As[cc][ty * 4];
            float4 a1 = *(const float4*)&As[cc][64 + ty * 4];
            float4 b0 = *(const float4*)&Bs[cc][tx * 4];
            float4 b1 = *(const float4*)&Bs[cc][64 + tx * 4];
            float ar[2][4] = {{a0.x, a0.y, a0.z, a0.w}, {a1.x, a1.y, a1.z, a1.w}};
            float br[2][4] = {{b0.x, b0.y, b0.z, b0.w}, {b1.x, b1.y, b1.z, b1.w}};
#pragma unroll
            for (int rh = 0; rh < 2; ++rh)
#pragma unroll
                for (int i = 0; i < 4; ++i)
#pragma unroll
                    for (int ch = 0; ch < 2; ++ch)
#pragma unroll
                        for (int j = 0; j < 4; ++j)
                            acc[rh][ch][i][j] = fmaf(ar[rh][i], br[ch][j], acc[rh][ch][i][j]);
        }
        __syncthreads();
    }
    float xr[2][4], xm[2][4];
#pragma unroll
    for (int rh = 0; rh < 2; ++rh)
#pragma unroll
        for (int i = 0; i < 4; ++i) xr[rh][i] = xx[p0 + rowbase + rh * 64 + ty * 4 + i];
#pragma unroll
    for (int ch = 0; ch < 2; ++ch)
#pragma unroll
        for (int j = 0; j < 4; ++j) xm[ch][j] = xx[p0 + colbase + ch * 64 + tx * 4 + j];
    // normal store: pd[r][m] = 2*acc - xx[r] - xx[m]
#pragma unroll
    for (int rh = 0; rh < 2; ++rh)
#pragma unroll
        for (int i = 0; i < 4; ++i) {
            int r = rowbase + rh * 64 + ty * 4 + i;
            float xrv = xr[rh][i];
#pragma unroll
            for (int ch = 0; ch < 2; ++ch) {
                int m = colbase + ch * 64 + tx * 4;
                float4 o;
                o.x = 2.f * acc[rh][ch][i][0] - xrv - xm[ch][0];
                o.y = 2.f * acc[rh][ch][i][1] - xrv - xm[ch][1];
                o.z = 2.f * acc[rh][ch][i][2] - xrv - xm[ch][2];
                o.w = 2.f * acc[rh][ch][i][3] - xrv - xm[ch][3];
                *(float4*)&pd[(size_t)r * NPT + m] = o;
            }
        }
    // mirrored store: pd[m][r] = 2*acc - xx[m] - xx[r]
    if (ti != tj) {
#pragma unroll
        for (int ch = 0; ch < 2; ++ch)
#pragma unroll
            for (int j = 0; j < 4; ++j) {
                int m = colbase + ch * 64 + tx * 4 + j;
                float xmv = xm[ch][j];
#pragma unroll
                for (int rh = 0; rh < 2; ++rh) {
                    float4 o;
                    o.x = 2.f * acc[rh][ch][0][j] - xmv - xr[rh][0];
                    o.y = 2.f * acc[rh][ch][1][j] - xmv - xr[rh][1];
                    o.z = 2.f * acc[rh][ch][2][j] - xmv - xr[rh][2];
                    o.w = 2.f * acc[rh][ch][3][j] - xmv - xr[rh][3];
                    *(float4*)&pd[(size_t)m * NPT + rowbase + rh * 64 + ty * 4] = o;
                }
            }
    }
}

// ---------------- shared topk core: per-lane top-2 + lazy rescan ----------------
// v[64] per lane; global col of v[j] = (j>>2)*256 + lane*4 + (j&3).
__device__ __forceinline__ void topk_core(float (&v)[64], int lane, int b,
                                          int* __restrict__ op) {
    float m1 = NEG_INF, m2 = NEG_INF;
    int j1 = 0, j2 = 0;
#pragma unroll
    for (int j = 0; j < 64; ++j) {
        float vv = v[j];
        bool c1 = vv > m1;          // strict > : earlier (smaller) j wins ties
        bool c2 = vv > m2;
        m2 = c1 ? m1 : (c2 ? vv : m2);
        j2 = c1 ? j1 : (c2 ? j : j2);
        m1 = c1 ? vv : m1;
        j1 = c1 ? j : j1;
    }
    bool have2 = true;
    unsigned long long remM = 0ull;
    for (int t = 0; t < 20; ++t) {
        int g1 = ((j1 >> 2) << 8) + (lane << 2) + (j1 & 3);
        float bv = m1; int gi = g1;
#pragma unroll
        for (int s = 1; s < 64; s <<= 1) {
            float ov = __shfl_xor(bv, s);
            int og = __shfl_xor(gi, s);
            if (ov > bv || (ov == bv && og < gi)) { bv = ov; gi = og; }
        }
        if (lane == 0) op[t] = b * NPT + gi;
        bool needscan = false;
        if (gi == g1) {             // this lane's candidate won
            remM |= 1ull << j1;
            if (have2) { m1 = m2; j1 = j2; have2 = false; }
            else needscan = true;
        }
        if (__any(needscan)) {
            if (needscan) {
                m1 = NEG_INF; m2 = NEG_INF; j1 = 0; j2 = 0;
#pragma unroll
                for (int j = 0; j < 64; ++j) {
                    bool alive = !((remM >> j) & 1ull);
                    float vv = alive ? v[j] : NEG_INF;
                    bool c1 = vv > m1;
                    bool c2 = vv > m2;
                    m2 = c1 ? m1 : (c2 ? vv : m2);
                    j2 = c1 ? j1 : (c2 ? j : j2);
                    m1 = c1 ? vv : m1;
                    j1 = c1 ? j : j1;
                }
                have2 = true;
            }
        }
    }
}

// ---------------- top-20 from materialized pd ----------------
__global__ __launch_bounds__(256) void topk20(const float* __restrict__ pd,
                                              int* __restrict__ idxout, int b) {
    int row = blockIdx.x * 4 + (threadIdx.x >> 6);
    int lane = threadIdx.x & 63;
    const float4* prow4 = (const float4*)(pd + (size_t)row * NPT);
    float v[64];
#pragma unroll
    for (int q = 0; q < 16; ++q) {
        float4 t = prow4[q * 64 + lane];
        v[q * 4 + 0] = t.x; v[q * 4 + 1] = t.y;
        v[q * 4 + 2] = t.z; v[q * 4 + 3] = t.w;
    }
    topk_core(v, lane, b, idxout + (size_t)(b * NPT + row) * 20);
}

// ---------------- layer-1 (C=1) fused pd+topk: pd computed inline ----------------
__global__ __launch_bounds__(256) void topk1(const float* __restrict__ X,
                                             const float* __restrict__ xx,
                                             int* __restrict__ idxout) {
    int b = blockIdx.y;
    int row = blockIdx.x * 4 + (threadIdx.x >> 6);
    int lane = threadIdx.x & 63;
    int p0 = b * NPT;
    float xr = X[p0 + row];
    float xxr = xx[p0 + row];
    const float4* xb4 = (const float4*)(X + p0);
    const float4* xxb4 = (const float4*)(xx + p0);
    float v[64];
#pragma unroll
    for (int q = 0; q < 16; ++q) {
        float4 xm = xb4[q * 64 + lane];
        float4 xxm = xxb4[q * 64 + lane];
        v[q * 4 + 0] = (2.f * (xr * xm.x) - xxr) - xxm.x;
        v[q * 4 + 1] = (2.f * (xr * xm.y) - xxr) - xxm.y;
        v[q * 4 + 2] = (2.f * (xr * xm.z) - xxr) - xxm.z;
        v[q * 4 + 3] = (2.f * (xr * xm.w) - xxr) - xxm.w;
    }
    topk_core(v, lane, b, idxout + (size_t)(b * NPT + row) * 20);
}

// ---------------- layer-1 U/T: outer product (C=1, O=64) ----------------
__global__ __launch_bounds__(256) void ut1(const float* __restrict__ X,
                                           const float* __restrict__ w,
                                           float* __restrict__ U,
                                           float* __restrict__ T) {
    int p = blockIdx.x * 4 + (threadIdx.x >> 6);
    int o = threadIdx.x & 63;
    float xv = X[p];
    float wa = w[o * 2];
    float wt = w[o * 2 + 1] - wa;
    U[(size_t)p * 64 + o] = wa * xv;
    T[(size_t)p * 64 + o] = wt * xv;
}

// ---------------- U = wA * X, T = (wB - wA) * X  (point-major out) ----------------
__global__ __launch_bounds__(256) void ut_gemm(const float* __restrict__ X,
                                               const float* __restrict__ w,
                                               float* __restrict__ U,
                                               float* __restrict__ T,
                                               int C, int O) {
    __shared__ float Xs[KC][PAD];
    __shared__ float Wa[KC][PAD];
    __shared__ float Wt[KC][PAD];
    int tid = threadIdx.x;
    int tx = tid & 15;
    int ty = tid >> 4;
    int pbase = blockIdx.x * 64;
    int obase = blockIdx.y * 64;
    int lc = tid & 15;
    int li = tid >> 4;
    float aU[4][4] = {}, aT[4][4] = {};
    for (int c0 = 0; c0 < C; c0 += KC) {
        int c = c0 + lc;
#pragma unroll
        for (int r = 0; r < 4; ++r) {
            int i = li + r * 16;
            Xs[lc][i] = X[(size_t)(pbase + i) * C + c];
            const float* wrow = w + (size_t)(obase + i) * (2 * C);
            float wa = wrow[c];
            Wa[lc][i] = wa;
            Wt[lc][i] = wrow[C + c] - wa;
        }
        __syncthreads();
#pragma unroll
        for (int cc = 0; cc < KC; ++cc) {
            float xv[4], wav[4], wtv[4];
#pragma unroll
            for (int i = 0; i < 4; ++i) xv[i] = Xs[cc][tx * 4 + i];
#pragma unroll
            for (int j = 0; j < 4; ++j) { wav[j] = Wa[cc][ty * 4 + j]; wtv[j] = Wt[cc][ty * 4 + j]; }
#pragma unroll
            for (int j = 0; j < 4; ++j)
#pragma unroll
                for (int i = 0; i < 4; ++i) {
                    aU[j][i] = fmaf(wav[j], xv[i], aU[j][i]);
                    aT[j][i] = fmaf(wtv[j], xv[i], aT[j][i]);
                }
        }
        __syncthreads();
    }
#pragma unroll
    for (int j = 0; j < 4; ++j)
#pragma unroll
        for (int i = 0; i < 4; ++i) {
            size_t p = pbase + tx * 4 + i;
            int o = obase + ty * 4 + j;
            U[p * O + o] = aU[j][i];
            T[p * O + o] = aT[j][i];
        }
}

// ---------------- gather neighbors, max over k, BN + LeakyReLU (float4 over o) ----
__global__ __launch_bounds__(256) void gather_max4(const float* __restrict__ U,
                                                   const float* __restrict__ T,
                                                   const int* __restrict__ idx,
                                                   const float* __restrict__ g,
                                                   const float* __restrict__ bb,
                                                   const float* __restrict__ rm,
                                                   const float* __restrict__ rv,
                                                   float* __restrict__ Xout, int O) {
    int tpp = O / 4;                      // threads per point
    int ppb = 256 / tpp;                  // points per block
    int lp = threadIdx.x / tpp;
    int o4 = (threadIdx.x % tpp) * 4;
    int p = blockIdx.x * ppb + lp;
    const int* ip = idx + (size_t)p * 20;
    float4 m = {NEG_INF, NEG_INF, NEG_INF, NEG_INF};
#pragma unroll
    for (int k = 0; k < 20; ++k) {
        int j = ip[k];
        float4 u = *(const float4*)&U[(size_t)j * O + o4];
        m.x = fmaxf(m.x, u.x); m.y = fmaxf(m.y, u.y);
        m.z = fmaxf(m.z, u.z); m.w = fmaxf(m.w, u.w);
    }
    float4 t = *(const float4*)&T[(size_t)p * O + o4];
    float4 gg = *(const float4*)&g[o4];
    float4 bv = *(const float4*)&bb[o4];
    float4 rmv = *(const float4*)&rm[o4];
    float4 rvv = *(const float4*)&rv[o4];
    float4 y;
    y.x = (m.x + t.x - rmv.x) * (gg.x / sqrtf(rvv.x + EPS)) + bv.x;
    y.y = (m.y + t.y - rmv.y) * (gg.y / sqrtf(rvv.y + EPS)) + bv.y;
    y.z = (m.z + t.z - rmv.z) * (gg.z / sqrtf(rvv.z + EPS)) + bv.z;
    y.w = (m.w + t.w - rmv.w) * (gg.w / sqrtf(rvv.w + EPS)) + bv.w;
    y.x = y.x > 0.f ? y.x : 0.2f * y.x;
    y.y = y.y > 0.f ? y.y : 0.2f * y.y;
    y.z = y.z > 0.f ? y.z : 0.2f * y.z;
    y.w = y.w > 0.f ? y.w : 0.2f * y.w;
    *(float4*)&Xout[(size_t)p * O + o4] = y;
}

// ---------------- head stage 1: 128 o x 128 p tile, 8x8/thread (single buffer) ----
__global__ __launch_bounds__(256) void head_partial(const float* __restrict__ X1,
                                                    const float* __restrict__ X2,
                                                    const float* __restrict__ X3,
                                                    const float* __restrict__ X4,
                                                    const float* __restrict__ w5,
                                                    const float* __restrict__ wreg,
                                                    const float* __restrict__ g,
                                                    const float* __restrict__ bb,
                                                    const float* __restrict__ rm,
                                                    const float* __restrict__ rv,
                                                    float* __restrict__ partial) {
    __shared__ __align__(16) float Ws[KC][PADB];   // A: o rows
    __shared__ __align__(16) float Hs[KC][PADB];   // B: p cols
    __shared__ float red[16][PADB];
    int tid = threadIdx.x;
    int tx = tid & 15;          // p group
    int ty = tid >> 4;          // o group
    int o0 = blockIdx.x * 128;  // 8 o-tiles
    int p0 = blockIdx.y * 128;  // 256 p-tiles
    int sc4 = (tid & 3) * 4;
    int spt = tid >> 2;
    float acc[2][2][4][4] = {}; // [rh(o)][ch(p)][i][j]
    for (int c0 = 0; c0 < 512; c0 += KC) {
        const float* src;
        int coff, Cs;
        if (c0 < 64)       { src = X1; coff = c0;       Cs = 64; }
        else if (c0 < 128) { src = X2; coff = c0 - 64;  Cs = 64; }
        else if (c0 < 256) { src = X3; coff = c0 - 128; Cs = 128; }
        else               { src = X4; coff = c0 - 256; Cs = 256; }
#pragma unroll
        for (int h = 0; h < 2; ++h) {
            int pt = spt + h * 64;
            float4 wv = *(const float4*)&w5[(size_t)(o0 + pt) * 512 + c0 + sc4];
            float4 hv = *(const float4*)&src[(size_t)(p0 + pt) * Cs + coff + sc4];
            Ws[sc4 + 0][pt] = wv.x; Ws[sc4 + 1][pt] = wv.y;
            Ws[sc4 + 2][pt] = wv.z; Ws[sc4 + 3][pt] = wv.w;
            Hs[sc4 + 0][pt] = hv.x; Hs[sc4 + 1][pt] = hv.y;
            Hs[sc4 + 2][pt] = hv.z; Hs[sc4 + 3][pt] = hv.w;
        }
        __syncthreads();
#pragma unroll
        for (int cc = 0; cc < KC; ++cc) {
            float4 a0 = *(const float4*)&Ws[cc][ty * 4];
            float4 a1 = *(const float4*)&Ws[cc][64 + ty * 4];
            float4 b0 = *(const float4*)&Hs[cc][tx * 4];
            float4 b1 = *(const float4*)&Hs[cc][64 + tx * 4];
            float ar[2][4] = {{a0.x, a0.y, a0.z, a0.w}, {a1.x, a1.y, a1.z, a1.w}};
            float br[2][4] = {{b0.x, b0.y, b0.z, b0.w}, {b1.x, b1.y, b1.z, b1.w}};
#pragma unroll
            for (int rh = 0; rh < 2; ++rh)
#pragma unroll
                for (int i = 0; i < 4; ++i)
#pragma unroll
                    for (int ch = 0; ch < 2; ++ch)
#pragma unroll
                        for (int j = 0; j < 4; ++j)
                            acc[rh][ch][i][j] = fmaf(ar[rh][i], br[ch][j], acc[rh][ch][i][j]);
        }
        __syncthreads();
    }
    float pacc[2][4] = {};
#pragma unroll
    for (int rh = 0; rh < 2; ++rh)
#pragma unroll
        for (int i = 0; i < 4; ++i) {
            int o = o0 + rh * 64 + ty * 4 + i;
            float scale = g[o] / sqrtf(rv[o] + EPS);
            float sm = rm[o], sb = bb[o], wr = wreg[o];
#pragma unroll
            for (int ch = 0; ch < 2; ++ch)
#pragma unroll
                for (int j = 0; j < 4; ++j) {
                    float y = (acc[rh][ch][i][j] - sm) * scale + sb;
                    y = y > 0.f ? y : 0.2f * y;
                    pacc[ch][j] = fmaf(wr, y, pacc[ch][j]);
                }
        }
#pragma unroll
    for (int ch = 0; ch < 2; ++ch)
#pragma unroll
        for (int j = 0; j < 4; ++j)
            red[ty][ch * 64 + tx * 4 + j] = pacc[ch][j];
    __syncthreads();
    if (tid < 128) {
        float s = 0.f;
#pragma unroll
        for (int q = 0; q < 16; ++q) s += red[q][tid];
        partial[(size_t)blockIdx.x * PTS + p0 + tid] = s;
    }
}

// ---------------- head stage 2: out[p] = sum over 8 o-tiles ----------------
__global__ __launch_bounds__(256) void head_reduce(const float* __restrict__ partial,
                                                   float* __restrict__ out) {
    int p = blockIdx.x * 256 + threadIdx.x;
    if (p >= PTS) return;
    float s = 0.f;
#pragma unroll
    for (int q = 0; q < 8; ++q) s += partial[(size_t)q * PTS + p];
    out[p] = s;
}

extern "C" void kernel_launch(void* const* d_in, const int* in_sizes, int n_in,
                              void* d_out, int out_size, void* d_ws, size_t ws_size,
                              hipStream_t stream) {
    const float* x    = (const float*)d_in[0];
    const float* w1   = (const float*)d_in[1];
    const float* w2   = (const float*)d_in[2];
    const float* w3   = (const float*)d_in[3];
    const float* w4   = (const float*)d_in[4];
    const float* w5   = (const float*)d_in[5];
    const float* wreg = (const float*)d_in[6];
    const float* bn[5][4];
    for (int t = 0; t < 5; ++t)
        for (int q = 0; q < 4; ++q)
            bn[t][q] = (const float*)d_in[7 + t * 4 + q];
    float* out = (float*)d_out;

    // workspace layout (bytes), peak ~131 MB (proven OK).
    char* ws = (char*)d_ws;
    size_t o_x1  = 0;
    size_t o_x2  = o_x1  + (size_t)PTS * 64 * 4;
    size_t o_x3  = o_x2  + (size_t)PTS * 64 * 4;
    size_t o_x4  = o_x3  + (size_t)PTS * 128 * 4;
    size_t o_idx = o_x4  + (size_t)PTS * 256 * 4;
    size_t o_xx  = o_idx + (size_t)PTS * 20 * 4;
    size_t o_pd  = o_xx  + (size_t)PTS * 4;
    size_t o_u   = o_pd;                            // alias: U over PD slab
    size_t o_t   = o_u   + (size_t)PTS * 256 * 4;

    float* X1 = (float*)(ws + o_x1);
    float* X2 = (float*)(ws + o_x2);
    float* X3 = (float*)(ws + o_x3);
    float* X4 = (float*)(ws + o_x4);
    int*   IDX = (int*)(ws + o_idx);
    float* XX = (float*)(ws + o_xx);
    float* PD = (float*)(ws + o_pd);
    float* U  = (float*)(ws + o_u);
    float* T  = (float*)(ws + o_t);
    float* PART = (float*)(ws + o_idx);   // 8*PTS*4 = 1 MB < IDX slab

    auto edge_block = [&](const float* Xin, int C, const float* w,
                          const float* const* bnp, float* Xout, int O) {
        sqnorm<<<PTS / 256, 256, 0, stream>>>(Xin, XX, C);
        if (C == 1) {
            topk1<<<dim3(NPT / 4, BATCH), 256, 0, stream>>>(Xin, XX, IDX);
            ut1<<<PTS / 4, 256, 0, stream>>>(Xin, w, U, T);
        } else {
            for (int b = 0; b < BATCH; ++b) {
                pd_sym128<<<528, 256, 0, stream>>>(Xin, XX, PD, C, b);
                topk20<<<NPT / 4, 256, 0, stream>>>(PD, IDX, b);
            }
            ut_gemm<<<dim3(PTS / 64, O / 64), 256, 0, stream>>>(Xin, w, U, T, C, O);
        }
        gather_max4<<<PTS * (O / 4) / 256, 256, 0, stream>>>(U, T, IDX,
                bnp[0], bnp[1], bnp[2], bnp[3], Xout, O);
    };

    edge_block(x,  1,   w1, bn[0], X1, 64);
    edge_block(X1, 64,  w2, bn[1], X2, 64);
    edge_block(X2, 64,  w3, bn[2], X3, 128);
    edge_block(X3, 128, w4, bn[3], X4, 256);

    head_partial<<<dim3(8, PTS / 128), 256, 0, stream>>>(X1, X2, X3, X4, w5, wreg,
            bn[4][0], bn[4][1], bn[4][2], bn[4][3], PART);
    head_reduce<<<PTS / 256, 256, 0, stream>>>(PART, out);
}